// Round 10
// baseline (3980.931 us; speedup 1.0000x reference)
//
#include <hip/hip_runtime.h>

#define HW 16384
#define BATCH 8

typedef unsigned short u16;
typedef __attribute__((ext_vector_type(8))) short bfrag;   // 8 bf16 in 4 VGPRs
typedef __attribute__((ext_vector_type(4))) float ffrag;   // MFMA accumulator
typedef __attribute__((ext_vector_type(4))) float f4v;

// ---------------------------------------------------------------------------
__device__ __forceinline__ u16 f2bf(float f) {
  unsigned int u = __float_as_uint(f);
  u += 0x7FFFu + ((u >> 16) & 1u);
  return (u16)(u >> 16);
}
__device__ __forceinline__ float bf2f(u16 h) {
  return __uint_as_float(((unsigned int)h) << 16);
}
__device__ __forceinline__ ffrag mfma16(bfrag a, bfrag b, ffrag c) {
  return __builtin_amdgcn_mfma_f32_16x16x32_bf16(a, b, c, 0, 0, 0);
}

__device__ __forceinline__ float spline_eval(float x, const float* __restrict__ c,
                                             int K, float xmin, float xmax) {
  float step = (xmax - xmin) / (float)(K - 1);
  float t = (x - xmin) / step;
  float fidx = floorf(t);
  fidx = fminf(fmaxf(fidx, 0.0f), (float)(K - 2));
  int idx = (int)fidx;
  float frac = t - fidx;
  return c[idx] * (1.0f - frac) + c[idx + 1] * frac;
}
__device__ __forceinline__ float spline31(float x, const float* __restrict__ c) {
  float t = x * 10.0f;
  float fi = floorf(t);
  fi = fminf(fmaxf(fi, 0.0f), 29.0f);
  int i = (int)fi;
  float fr = t - fi;
  return c[i] * (1.0f - fr) + c[i + 1] * fr;
}

// ---------------------------------------------------------------------------
// Weight prep: OIHW fp32 -> MFMA B-fragment order, bf16 hi/lo planes. (r4-r11)
// ---------------------------------------------------------------------------
template<int KS, int CIW, int CO, int NTT, int NSLICE, int TAPS, int CHUNKS, bool TR>
__global__ void k_prepw(const float* __restrict__ W, u16* __restrict__ hi,
                        u16* __restrict__ lo) {
  int gid = blockIdx.x * 256 + threadIdx.x;
  const int total = NSLICE * CHUNKS * NTT * 64;
  if (gid >= total) return;
  int L = gid & 63;
  int rest = gid >> 6;
  int ntg = rest % NTT; rest /= NTT;
  int ch = rest % CHUNKS;
  int sl = rest / CHUNKS;
  int q = L >> 4, n = L & 15;
  int tap = ch * 4 + q;
  int co = ntg * 16 + n;
  int dh = tap / KS, dw = tap - dh * KS;
  for (int j = 0; j < 8; ++j) {
    int ci = sl * 8 + j;
    float v = 0.0f;
    if (tap < TAPS && co < CO) {
      if (TR)
        v = W[(((size_t)ci * CO + co) * KS + (KS - 1 - dh)) * KS + (KS - 1 - dw)];
      else
        v = W[(((size_t)co * CIW + ci) * KS + dh) * KS + dw];
    }
    u16 h = f2bf(v);
    hi[(size_t)gid * 8 + j] = h;
    lo[(size_t)gid * 8 + j] = f2bf(v - bf2f(h));
  }
}

// ---------------------------------------------------------------------------
// bconv (r6-verified core + KSPLIT; plain staging — dbuf regressed in r14):
// LDS-staged 1-term bf16 MFMA conv.
// KSPLIT>1: blockIdx.z = K-slice group (co-group fixed 0), partial fp32 out.
// EPI 3: v*m^2 -> slice-major bf16 (128ch)
// EPI 5: partial fp32, co<8 -> part[(bz*BATCH+bb)*HW + px]*8 + co
// ---------------------------------------------------------------------------
template<int KS, int SLICES, int TAPS, int CHUNKS, int NT, int NTT, int KSPLIT, int EPI>
__global__ __launch_bounds__(256) void bconv(
    const u16* __restrict__ in, const u16* __restrict__ wHi,
    float* __restrict__ outF, u16* __restrict__ outBf,
    const u16* __restrict__ mskc)
{
  constexpr int P   = KS / 2;
  constexpr int IW  = 16 + 2 * P;
  constexpr int IH  = 16 + 2 * P;
  constexpr int SPB = SLICES / KSPLIT;

  __shared__ __align__(16) u16 sA[IH * IW * 8];

  const int tid = threadIdx.x;
  const int wv  = tid >> 6;
  const int L   = tid & 63;
  const int q   = L >> 4;
  const int n16 = L & 15;

  const int tx = blockIdx.x & 7, ty = blockIdx.x >> 3;
  const int w0 = tx * 16, h0 = ty * 16;
  const int bb = blockIdx.y;
  const int bz = blockIdx.z;
  const int slc0 = (KSPLIT > 1) ? bz * SPB : 0;
  const int cog  = (KSPLIT > 1) ? 0 : bz;

  ffrag acc[4][NT];
#pragma unroll
  for (int i = 0; i < 4; ++i)
#pragma unroll
    for (int t = 0; t < NT; ++t) acc[i][t] = (ffrag)0.0f;

  for (int s = 0; s < SPB; ++s) {
    const int slc = slc0 + s;
    __syncthreads();
    for (int e = tid; e < IH * IW; e += 256) {
      int ih = e / IW, iw = e - ih * IW;
      int gh = h0 + ih - P, gw = w0 + iw - P;
      f4v v = (f4v)0.0f;
      if (gh >= 0 && gh < 128 && gw >= 0 && gw < 128)
        v = *(const f4v*)(in + (((size_t)(bb * SLICES + slc) * HW) + gh * 128 + gw) * 8);
      *(f4v*)(sA + (size_t)e * 8) = v;
    }
    __syncthreads();

    const u16* wS = wHi + (size_t)slc * CHUNKS * NTT * 512;
    for (int ch = 0; ch < CHUNKS; ++ch) {
      int tap = ch * 4 + q;
      int dh = 0, dw = 0;
      if (tap < TAPS) { dh = tap / KS; dw = tap - dh * KS; }
      int toff = dh * IW + dw;
      bfrag A[4];
#pragma unroll
      for (int i = 0; i < 4; ++i)
        A[i] = *(const bfrag*)(sA + ((wv * 4 + i) * IW + n16 + toff) * 8);
#pragma unroll
      for (int t = 0; t < NT; ++t) {
        bfrag B = *(const bfrag*)(wS + ((size_t)ch * NTT + cog * NT + t) * 512 + L * 8);
#pragma unroll
        for (int i = 0; i < 4; ++i) acc[i][t] = mfma16(A[i], B, acc[i][t]);
      }
    }
  }

#pragma unroll
  for (int i = 0; i < 4; ++i) {
    const int h = h0 + wv * 4 + i;
#pragma unroll
    for (int t = 0; t < NT; ++t) {
      const int co = cog * (NT * 16) + t * 16 + n16;
#pragma unroll
      for (int r = 0; r < 4; ++r) {
        const int w = w0 + q * 4 + r;
        float v = acc[i][t][r];
        if (EPI == 3) {
          size_t o = (((size_t)(bb * 16 + (co >> 3)) * HW) + h * 128 + w) * 8 + (co & 7);
          float m = bf2f(mskc[o]);
          outBf[o] = f2bf(v * m * m);
        } else if (EPI == 5) {
          if (n16 < 8)
            outF[(((size_t)bz * BATCH + bb) * HW + h * 128 + w) * 8 + n16] = v;
        }
      }
    }
  }
}

// ---------------------------------------------------------------------------
// mconv (r14: TH=16, pre-split bf16 hi/lo input, double-buffered staging;
// r20: KS=3 instances moved to NT=2/z=4 — 70us floor analysis says MFMA ~10us
// + HBM ~12us, so the 70us is barrier-latency at 2 blocks/CU; 4 blocks/CU
// doubles hiding, B-reuse loss is L2-cheap): 3-term split MFMA conv.
// EPI 4: spline31(|v|) -> hi/lo bf16 slice-major planes
// EPI 2: clip spline -> mask_c bf16
// ---------------------------------------------------------------------------
template<int KS, int CIN, int NSLICE, int TAPS, int CHUNKS,
         int TH, int MTW, int NT, int NTT, int EPI>
__global__ __launch_bounds__(256) void mconv(
    const u16* __restrict__ inH, const u16* __restrict__ inL,
    const u16* __restrict__ wHi, const u16* __restrict__ wLo,
    u16* __restrict__ outH, u16* __restrict__ outL,
    u16* __restrict__ outBf,
    const float* __restrict__ sp, const float* __restrict__ sl,
    int binOfs, int boutOfs)
{
  constexpr int P  = KS / 2;
  constexpr int IW = 16 + 2 * P;
  constexpr int IH = TH + 2 * P;
  constexpr int NE = (IH * IW + 255) / 256;

  __shared__ __align__(16) u16 sHi[IH * IW * 8];
  __shared__ __align__(16) u16 sLo[IH * IW * 8];

  const int tid = threadIdx.x;
  const int wv  = tid >> 6;
  const int L   = tid & 63;
  const int q   = L >> 4;
  const int n16 = L & 15;

  const int tx = blockIdx.x & 7;
  const int ty = blockIdx.x >> 3;
  const int w0 = tx * 16, h0 = ty * TH;
  const int bin  = (int)blockIdx.y + binOfs;
  const int bout = (int)blockIdx.y + boutOfs;
  const int bz = blockIdx.z;

  ffrag acc[MTW][NT];
#pragma unroll
  for (int i = 0; i < MTW; ++i)
#pragma unroll
    for (int t = 0; t < NT; ++t) acc[i][t] = (ffrag)0.0f;

  auto ldslice = [&](int slc, f4v* ph, f4v* pl) {
#pragma unroll
    for (int k = 0; k < NE; ++k) {
      int e = tid + k * 256;
      ph[k] = (f4v)0.0f;
      pl[k] = (f4v)0.0f;
      if (e < IH * IW) {
        int ih = e / IW, iw = e - ih * IW;
        int gh = h0 + ih - P, gw = w0 + iw - P;
        if (gh >= 0 && gh < 128 && gw >= 0 && gw < 128) {
          size_t o = (((size_t)(bin * NSLICE + slc) * HW) + gh * 128 + gw) * 8;
          ph[k] = *(const f4v*)(inH + o);
          pl[k] = *(const f4v*)(inL + o);
        }
      }
    }
  };

  f4v rh[NE], rl[NE];
  ldslice(0, rh, rl);

  for (int slc = 0; slc < NSLICE; ++slc) {
    __syncthreads();
#pragma unroll
    for (int k = 0; k < NE; ++k) {
      int e = tid + k * 256;
      if (e < IH * IW) {
        *(f4v*)(sHi + (size_t)e * 8) = rh[k];
        *(f4v*)(sLo + (size_t)e * 8) = rl[k];
      }
    }
    f4v nh[NE], nl[NE];
    if (slc + 1 < NSLICE) {
      ldslice(slc + 1, nh, nl);
    } else {
#pragma unroll
      for (int k = 0; k < NE; ++k) { nh[k] = (f4v)0.0f; nl[k] = (f4v)0.0f; }
    }
    __syncthreads();

    const u16* wHs = wHi + (size_t)slc * CHUNKS * NTT * 512;
    const u16* wLs = wLo + (size_t)slc * CHUNKS * NTT * 512;
    for (int ch = 0; ch < CHUNKS; ++ch) {
      int tap = ch * 4 + q;
      int dh = tap / KS;
      int dw = tap - dh * KS;
      int toff = (tap < TAPS) ? (dh * IW + dw) : 0;
      bfrag Ah[MTW], Al[MTW];
#pragma unroll
      for (int i = 0; i < MTW; ++i) {
        int a8 = ((wv * MTW + i) * IW + n16 + toff) * 8;
        Ah[i] = *(const bfrag*)(sHi + a8);
        Al[i] = *(const bfrag*)(sLo + a8);
      }
#pragma unroll
      for (int t = 0; t < NT; ++t) {
        size_t off = ((size_t)ch * NTT + bz * NT + t) * 512 + L * 8;
        bfrag Bh = *(const bfrag*)(wHs + off);
        bfrag Bl = *(const bfrag*)(wLs + off);
#pragma unroll
        for (int i = 0; i < MTW; ++i) {
          acc[i][t] = mfma16(Ah[i], Bh, acc[i][t]);
          acc[i][t] = mfma16(Ah[i], Bl, acc[i][t]);
          acc[i][t] = mfma16(Al[i], Bh, acc[i][t]);
        }
      }
    }
#pragma unroll
    for (int k = 0; k < NE; ++k) { rh[k] = nh[k]; rl[k] = nl[k]; }
  }

#pragma unroll
  for (int i = 0; i < MTW; ++i) {
    const int h = h0 + wv * MTW + i;
#pragma unroll
    for (int t = 0; t < NT; ++t) {
      const int co = bz * (NT * 16) + t * 16 + n16;
#pragma unroll
      for (int r = 0; r < 4; ++r) {
        const int w = w0 + q * 4 + r;
        float v = acc[i][t][r];
        if (EPI == 4) {
          float x = spline31(fabsf(v), sp);
          u16 hb = f2bf(x);
          size_t o = (((size_t)(bout * 16 + (co >> 3)) * HW) + h * 128 + w) * 8 + (co & 7);
          outH[o] = hb;
          outL[o] = f2bf(x - bf2f(hb));
        } else if (EPI == 2) {
          float s = sl[bout * 128 + co];
          float x = spline31(s * fabsf(v), sp);
          x = fminf(fmaxf(x, 0.01f), 1.0f);
          size_t o = (((size_t)(bout * 16 + (co >> 3)) * HW) + h * 128 + w) * 8 + (co & 7);
          outBf[o] = f2bf(x);
        }
      }
    }
  }
}

// ---------------------------------------------------------------------------
// fused forward 1->4->8 (r16: 16x16 tile; r18: plain bounds; r19: p-update
// fused into staging; r20: stage-2 co-loop split into 2 sequential passes of
// 4 (#pragma unroll 1) — VGPR was 176 = 2 waves/SIMD; halved acc+weight
// liveness should land <=128 -> 4 waves/SIMD. Per-co accumulation order
// unchanged -> bit-exact).
// OUT 0: fp32 NHWC8 | OUT 1: bf16 8ch | OUT 2: bf16 hi/lo 8ch planes
// ---------------------------------------------------------------------------
template<int OUT>
__global__ __launch_bounds__(256) void fused_fwd(
    const float* __restrict__ in, const float* __restrict__ wA,
    const float* __restrict__ wB, float* __restrict__ outF,
    u16* __restrict__ outBf, u16* __restrict__ outLo,
    const float* __restrict__ rr, const float* __restrict__ pold,
    float* __restrict__ pnew, const float* __restrict__ rnp,
    const float* __restrict__ rnn)
{
  __shared__ float sX[32 * 32];
  __shared__ float sT4[4][24 * 25];
  __shared__ float sWA[81 * 4];
  __shared__ float sWB[4 * 81 * 8];

  const int tid = threadIdx.x;
  const int b   = blockIdx.z;
  const int h0  = (blockIdx.x >> 3) * 16;
  const int w0  = (blockIdx.x & 7) * 16;

  const bool doP = (rnp != nullptr);
  float beta = 0.0f;
  if (doP) {
    float rnb = rnp[b];
    beta = (rnb > 1e-6f) ? (rnn[b] / rnb) : 0.0f;
  }

  for (int e = tid; e < 1024; e += 256) {
    int r = e >> 5, c = e & 31;
    int gh = h0 - 8 + r, gw = w0 - 8 + c;
    float v = 0.0f;
    if (gh >= 0 && gh < 128 && gw >= 0 && gw < 128) {
      size_t idx = (size_t)b * HW + gh * 128 + gw;
      if (doP) {
        v = rr[idx] + beta * pold[idx];
        if (r >= 8 && r < 24 && c >= 8 && c < 24) pnew[idx] = v;
      } else {
        v = in[idx];
      }
    }
    sX[e] = v;
  }
  for (int e = tid; e < 324; e += 256) {
    int co = e & 3, tap = e >> 2;
    sWA[tap * 4 + co] = wA[co * 81 + tap];
  }
  for (int e = tid; e < 2592; e += 256) {
    int co = e & 7;
    int rest = e >> 3;
    int tap = rest % 81, ci = rest / 81;
    sWB[(ci * 81 + tap) * 8 + co] = wB[((size_t)co * 4 + ci) * 81 + tap];
  }
  __syncthreads();

  for (int e = tid; e < 576; e += 256) {
    int r = e / 24, c = e - (e / 24) * 24;
    int gh = h0 - 4 + r, gw = w0 - 4 + c;
    float a0 = 0.0f, a1 = 0.0f, a2 = 0.0f, a3 = 0.0f;
    if (gh >= 0 && gh < 128 && gw >= 0 && gw < 128) {
      for (int kh = 0; kh < 9; ++kh) {
#pragma unroll
        for (int kw = 0; kw < 9; ++kw) {
          float x = sX[(r + kh) * 32 + (c + kw)];
          const float* wp = &sWA[(kh * 9 + kw) * 4];
          a0 += x * wp[0]; a1 += x * wp[1]; a2 += x * wp[2]; a3 += x * wp[3];
        }
      }
    }
    sT4[0][r * 25 + c] = a0;
    sT4[1][r * 25 + c] = a1;
    sT4[2][r * 25 + c] = a2;
    sT4[3][r * 25 + c] = a3;
  }
  __syncthreads();

  const int c  = tid & 15;
  const int r0 = tid >> 4;
  const int h  = h0 + r0;
  const int w  = w0 + c;

#pragma unroll 1
  for (int half = 0; half < 2; ++half) {
    float acc[4];
#pragma unroll
    for (int co = 0; co < 4; ++co) acc[co] = 0.0f;

    for (int ci = 0; ci < 4; ++ci) {
      const float* t4c = sT4[ci];
      for (int kh = 0; kh < 9; ++kh) {
#pragma unroll
        for (int kw = 0; kw < 9; ++kw) {
          float x0 = t4c[(r0 + kh) * 25 + c + kw];
          const float* wp = &sWB[(ci * 81 + kh * 9 + kw) * 8 + half * 4];
#pragma unroll
          for (int co = 0; co < 4; ++co) acc[co] += x0 * wp[co];
        }
      }
    }

#pragma unroll
    for (int co4 = 0; co4 < 4; ++co4) {
      int co = half * 4 + co4;
      float v = acc[co4];
      if (OUT == 0) {
        outF[(((size_t)b * 128 + h) * 128 + w) * 8 + co] = v;
      } else if (OUT == 1) {
        outBf[((size_t)b * HW + h * 128 + w) * 8 + co] = f2bf(v);
      } else {
        u16 hb = f2bf(v);
        size_t o = ((size_t)b * HW + h * 128 + w) * 8 + co;
        outBf[o] = hb;
        outLo[o] = f2bf(v - bf2f(hb));
      }
    }
  }
}

// ---------------------------------------------------------------------------
// fused tail (r17: 384 threads — middle stage 288 items single-pass,
// occupancy 8 -> 12 waves/CU; r6-vs-r8 A/B says within-noise — kept).
// 8 ->(9x9 t-conv) 4 ->(9x9 t-conv) 1, then (vin + lam*v)/(1+lam);
// per-block <vin, vout> partial -> atomicAdd den[b]. grid (64,1,8).
// ---------------------------------------------------------------------------
__global__ __launch_bounds__(384) void fused_tail(
    const float* __restrict__ part, const float* __restrict__ w11,
    const float* __restrict__ w10, const float* __restrict__ vin,
    const float* __restrict__ lam, float* __restrict__ vout,
    float* __restrict__ den)
{
  __shared__ float sX[8][1057];
  __shared__ float sT4[4][24 * 25];
  __shared__ float sW1[8 * 81 * 4];
  __shared__ float sW0[4 * 81];
  __shared__ float sRed[256];

  const int tid = threadIdx.x;
  const int b   = blockIdx.z;
  const int h0  = (blockIdx.x >> 3) * 16;
  const int w0  = (blockIdx.x & 7) * 16;

  for (int e = tid; e < 1024; e += 384) {
    int r = e >> 5, c = e & 31;
    int gh = h0 - 8 + r, gw = w0 - 8 + c;
    float v[8];
#pragma unroll
    for (int ci = 0; ci < 8; ++ci) v[ci] = 0.0f;
    if (gh >= 0 && gh < 128 && gw >= 0 && gw < 128) {
      const float* s = part + ((size_t)b * HW + gh * 128 + gw) * 8;
#pragma unroll
      for (int z = 0; z < 4; ++z) {
        f4v a  = *(const f4v*)(s + (size_t)z * 1048576);
        f4v b2 = *(const f4v*)(s + (size_t)z * 1048576 + 4);
        v[0] += a[0]; v[1] += a[1]; v[2] += a[2]; v[3] += a[3];
        v[4] += b2[0]; v[5] += b2[1]; v[6] += b2[2]; v[7] += b2[3];
      }
    }
#pragma unroll
    for (int ci = 0; ci < 8; ++ci) sX[ci][r * 33 + c] = v[ci];
  }
  for (int e = tid; e < 2592; e += 384) {
    int co = e & 3;
    int rest = e >> 2;
    int tap = rest % 81, ci = rest / 81;
    sW1[(ci * 81 + tap) * 4 + co] = w11[(size_t)(ci * 4 + co) * 81 + (80 - tap)];
  }
  for (int e = tid; e < 324; e += 384) {
    int tap = e % 81, ci = e / 81;
    sW0[ci * 81 + tap] = w10[(size_t)ci * 81 + (80 - tap)];
  }
  __syncthreads();

  for (int e = tid; e < 288; e += 384) {
    int r = e / 12, c2 = (e - r * 12) * 2;
    int gh = h0 - 4 + r;
    int gw0 = w0 - 4 + c2;
    float a0[4] = {0, 0, 0, 0}, a1[4] = {0, 0, 0, 0};
    for (int ci = 0; ci < 8; ++ci) {
      for (int kh = 0; kh < 9; ++kh) {
        const float* xb = &sX[ci][(r + kh) * 33 + c2];
#pragma unroll
        for (int kw = 0; kw < 9; ++kw) {
          float x0 = xb[kw], x1 = xb[kw + 1];
          const float* wp = &sW1[(ci * 81 + kh * 9 + kw) * 4];
#pragma unroll
          for (int co = 0; co < 4; ++co) {
            a0[co] += x0 * wp[co];
            a1[co] += x1 * wp[co];
          }
        }
      }
    }
    bool in0 = (gh >= 0 && gh < 128 && gw0 >= 0 && gw0 < 128);
    bool in1 = (gh >= 0 && gh < 128 && (gw0 + 1) >= 0 && (gw0 + 1) < 128);
#pragma unroll
    for (int co = 0; co < 4; ++co) {
      sT4[co][r * 25 + c2]     = in0 ? a0[co] : 0.0f;
      sT4[co][r * 25 + c2 + 1] = in1 ? a1[co] : 0.0f;
    }
  }
  __syncthreads();

  if (tid < 256) {
    int r = tid >> 4, c = tid & 15;
    float acc = 0.0f;
    for (int ci = 0; ci < 4; ++ci) {
      for (int kh = 0; kh < 9; ++kh) {
        const float* xb = &sT4[ci][(r + kh) * 25 + c];
        const float* wp = &sW0[ci * 81 + kh * 9];
#pragma unroll
        for (int kw = 0; kw < 9; ++kw) acc += xb[kw] * wp[kw];
      }
    }
    size_t o = (size_t)b * HW + (h0 + r) * 128 + (w0 + c);
    float l = lam[b];
    float vi = vin[o];
    float res = (vi + l * acc) / (1.0f + l);
    vout[o] = res;
    sRed[tid] = vi * res;
  }
  __syncthreads();
  for (int st = 128; st > 0; st >>= 1) {
    if (tid < st) sRed[tid] += sRed[tid + st];
    __syncthreads();
  }
  if (tid == 0) atomicAdd(&den[b], sRed[0]);
}

// ---------------------------------------------------------------------------
// helpers
// ---------------------------------------------------------------------------
__global__ void k_scalars(const float* __restrict__ sigma, const float* __restrict__ c_lam,
                          const float* __restrict__ c_scal, float* __restrict__ lam,
                          float* __restrict__ scal) {
  int tid = threadIdx.x;
  if (tid < BATCH) lam[tid] = spline_eval(sigma[tid], c_lam, 53, -1.0f, 51.0f);
  for (int j = tid; j < BATCH * 128; j += 256) {
    int b = j >> 7, chn = j & 127;
    float s = sigma[b];
    scal[j] = expf(spline_eval(s, c_scal + chn * 14, 14, -1.0f, 51.0f)) / (s + 1e-5f);
  }
}

// r16: also zeroes the 256-float CG scalar-slot region (rnbuf+denbuf)
__global__ void k_binit(const float* __restrict__ y, const float* __restrict__ lam,
                        float* __restrict__ bimg, float* __restrict__ x,
                        float* __restrict__ cgscal) {
  int i = blockIdx.x * 256 + threadIdx.x;
  int b = i >> 14;
  bimg[i] = y[i] / (1.0f + lam[b]);
  x[i] = 0.0f;
  if (blockIdx.x == 0) cgscal[threadIdx.x] = 0.0f;
}

// mask for c_k = 0 (bit-exact, r11-verified)
__global__ void k_fillmask(const float* __restrict__ c_sp3, u16* __restrict__ mask_c) {
  u16 hv = f2bf(fminf(fmaxf(c_sp3[0], 0.01f), 1.0f));
  u16 tmp[8];
#pragma unroll
  for (int j = 0; j < 8; ++j) tmp[j] = hv;
  size_t i = ((size_t)blockIdx.x * 256 + threadIdx.x) * 8;
  *(f4v*)(mask_c + i) = *(const f4v*)tmp;
}

// ---------------------------------------------------------------------------
// r16 parallel CG kernels. Per-iteration rn/den slots (pre-zeroed) remove all
// scalar-rotation races; grid (32,8) = 256 blocks. r19: k_cg2b removed —
// the p-update is fused into the next BtB's fused_fwd staging.
// ---------------------------------------------------------------------------
// r = p = bimg [- Bp]; atomicAdd <r,r> into rnout[b].
__global__ __launch_bounds__(256) void k_cg0p(
    const float* __restrict__ bimg, const float* __restrict__ Bp,
    float* __restrict__ r, float* __restrict__ p, float* __restrict__ rnout) {
  __shared__ float s[256];
  int b = blockIdx.y;
  size_t base = ((size_t)b << 14) + (size_t)blockIdx.x * 512;
  float local = 0.0f;
  for (int i = threadIdx.x; i < 512; i += 256) {
    float v = bimg[base + i];
    if (Bp) v -= Bp[base + i];
    r[base + i] = v;
    p[base + i] = v;
    local += v * v;
  }
  s[threadIdx.x] = local;
  __syncthreads();
  for (int st = 128; st > 0; st >>= 1) {
    if (threadIdx.x < st) s[threadIdx.x] += s[threadIdx.x + st];
    __syncthreads();
  }
  if (threadIdx.x == 0) atomicAdd(&rnout[b], s[0]);
}

// alpha = rnp/deng (guarded); x += alpha p (opt xout); r -= alpha Bp;
// atomicAdd <r',r'> into rnn[b].
__global__ __launch_bounds__(256) void k_cg2a(
    float* __restrict__ x, float* __restrict__ r, const float* __restrict__ p,
    const float* __restrict__ Bp, const float* __restrict__ rnp,
    const float* __restrict__ deng, float* __restrict__ rnn,
    float* __restrict__ xout) {
  __shared__ float s[256];
  int b = blockIdx.y;
  size_t base = ((size_t)b << 14) + (size_t)blockIdx.x * 512;
  float rnb = rnp[b];
  bool act = rnb > 1e-6f;
  float alpha = act ? rnb / deng[b] : 0.0f;
  float local = 0.0f;
  for (int i = threadIdx.x; i < 512; i += 256) {
    float pv = p[base + i];
    float xv = x[base + i] + alpha * pv;
    x[base + i] = xv;
    if (xout) xout[base + i] = xv;
    float rr = r[base + i] - alpha * Bp[base + i];
    r[base + i] = rr;
    local += rr * rr;
  }
  s[threadIdx.x] = local;
  __syncthreads();
  for (int st = 128; st > 0; st >>= 1) {
    if (threadIdx.x < st) s[threadIdx.x] += s[threadIdx.x + st];
    __syncthreads();
  }
  if (threadIdx.x == 0) atomicAdd(&rnn[b], s[0]);
}

// ---------------------------------------------------------------------------
extern "C" void kernel_launch(void* const* d_in, const int* in_sizes, int n_in_,
                              void* d_out, int out_size, void* d_ws, size_t ws_size,
                              hipStream_t stream) {
  const float* y      = (const float*)d_in[0];
  const float* sigma  = (const float*)d_in[1];
  const float* w1_0   = (const float*)d_in[2];
  const float* w1_1   = (const float*)d_in[3];
  const float* w1_2   = (const float*)d_in[4];
  const float* m1_0   = (const float*)d_in[5];
  const float* m1_1   = (const float*)d_in[6];
  const float* m1_2   = (const float*)d_in[7];
  const float* m2_w   = (const float*)d_in[8];
  const float* m3_w   = (const float*)d_in[9];
  const float* c_sp1  = (const float*)d_in[10];
  const float* c_sp2  = (const float*)d_in[11];
  const float* c_sp3  = (const float*)d_in[12];
  const float* c_lam  = (const float*)d_in[13];
  const float* c_scal = (const float*)d_in[14];
  // n_out = 2, n_in = 6 fixed by setup_inputs

  char* cur = (char*)d_ws;
  auto alloc = [&](size_t bytes) {
    char* p = cur;
    cur += (bytes + 255) & ~(size_t)255;
    return p;
  };

  // weight fragments (~3 MB)
  u16* wA_hi  = (u16*)alloc(86016 * 2);
  u16* wA_lo  = (u16*)alloc(86016 * 2);
  u16* wAm_hi = (u16*)alloc(86016 * 2);
  u16* wAm_lo = (u16*)alloc(86016 * 2);
  u16* wB_hi  = (u16*)alloc(172032 * 2);
  u16* wB_lo  = (u16*)alloc(172032 * 2);
  u16* wC2_hi = (u16*)alloc(196608 * 2);
  u16* wC2_lo = (u16*)alloc(196608 * 2);
  u16* wC3_hi = (u16*)alloc(196608 * 2);
  u16* wC3_lo = (u16*)alloc(196608 * 2);

  // region1 (67.1 MB): mask phase = P1 hi/lo bf16 planes; CG = big2c bf16
  char* region1 = alloc((size_t)16777216 * 4);
  u16* P1h   = (u16*)region1;
  u16* P1l   = (u16*)(region1 + (size_t)16777216 * 2);
  u16* big2c = (u16*)region1;
  // mask_c bf16 slice-major (33.5 MB)
  u16* mask_c = (u16*)alloc((size_t)16777216 * 2);
  // region2 (33.6 MB): mask = P2 hi/lo planes x4 batches; CG = part fp32
  char* region2 = alloc((size_t)4 * 128 * 128 * 128 * 4);
  u16*   P2h  = (u16*)region2;
  u16*   P2l  = (u16*)(region2 + (size_t)8388608 * 2);
  float* part = (float*)region2;                          // 4 x 1048576 fp32
  // region3 (4.2 MB): mask = t8 hi/lo planes; CG = t8c bf16 slice-major
  char* region3 = alloc((size_t)1048576 * 4);
  u16* t8h = (u16*)region3;
  u16* t8l = (u16*)(region3 + (size_t)1048576 * 2);
  u16* t8c = (u16*)region3;

  float* bimg  = (float*)alloc(131072 * 4);
  float* xbuf  = (float*)alloc(131072 * 4);
  float* rbuf  = (float*)alloc(131072 * 4);
  float* pbuf  = (float*)alloc(131072 * 4);
  float* pbuf2 = (float*)alloc(131072 * 4);   // r19: p ping-pong partner
  float* Bp    = (float*)alloc(131072 * 4);
  float* lam   = (float*)alloc(8 * 4);
  float* scal  = (float*)alloc(1024 * 4);
  // r16: CG scalar slots — rnbuf[16][8] then denbuf[16][8], zeroed in k_binit
  float* cgscal = (float*)alloc(256 * 4);
  float* rnbuf  = cgscal;
  float* denbuf = cgscal + 128;
  // total ~145 MB

  const dim3 blk(256);
  const dim3 blk384(384);
  const dim3 cgrid(32, 8);

  k_prepw<9, 8, 128, 8, 1, 81, 21, false><<<dim3(42), blk, 0, stream>>>(w1_2, wA_hi, wA_lo);
  k_prepw<9, 8, 128, 8, 1, 81, 21, false><<<dim3(42), blk, 0, stream>>>(m1_2, wAm_hi, wAm_lo);
  k_prepw<9, 8, 8, 1, 16, 81, 21, true><<<dim3(84), blk, 0, stream>>>(w1_2, wB_hi, wB_lo);
  k_prepw<3, 128, 128, 8, 16, 9, 3, false><<<dim3(96), blk, 0, stream>>>(m2_w, wC2_hi, wC2_lo);
  k_prepw<3, 128, 128, 8, 16, 9, 3, false><<<dim3(96), blk, 0, stream>>>(m3_w, wC3_hi, wC3_lo);

  k_scalars<<<dim3(1), blk, 0, stream>>>(sigma, c_lam, c_scal, lam, scal);
  k_binit<<<dim3(512), blk, 0, stream>>>(y, lam, bimg, xbuf, cgscal);

  // BtB: fused_fwd optionally computes p_new = r + beta*p_old during staging
  // (rnp != nullptr), writing interior pixels to pnew; downstream kernels
  // then consume pnew. vin is used only in plain mode.
  auto BtB = [&](const float* vin, float* vout, float* denp,
                 const float* rnp, const float* rnn,
                 const float* pold, float* pnew) {
    fused_fwd<1><<<dim3(64, 1, 8), blk, 0, stream>>>(
        vin, w1_0, w1_1, nullptr, t8c, nullptr, rbuf, pold, pnew, rnp, rnn);
    bconv<9, 1, 81, 21, 2, 8, 1, 3><<<dim3(64, 8, 4), blk, 0, stream>>>(
        t8c, wA_hi, nullptr, big2c, mask_c);
    bconv<9, 16, 81, 21, 1, 1, 4, 5><<<dim3(64, 8, 4), blk, 0, stream>>>(
        big2c, wB_hi, part, nullptr, nullptr);
    const float* tailvin = rnp ? (const float*)pnew : vin;
    fused_tail<<<dim3(64, 1, 8), blk384, 0, stream>>>(
        part, w1_1, w1_0, tailvin, lam, vout, denp);
  };

  // ================= outer 0: c_k = 0 (algebraic, r11-verified) =============
  // rn slots 0..6, den slots 0..5
  k_fillmask<<<dim3(8192), blk, 0, stream>>>(c_sp3, mask_c);
  k_cg0p<<<cgrid, blk, 0, stream>>>(bimg, nullptr, rbuf, pbuf, rnbuf + 0 * 8);
  {
    float* pc = pbuf;   // current p
    float* pa = pbuf2;  // alternate
    for (int it = 0; it < 6; ++it) {
      if (it == 0) {
        BtB(pc, Bp, denbuf + it * 8, nullptr, nullptr, nullptr, nullptr);
      } else {
        BtB(nullptr, Bp, denbuf + it * 8,
            rnbuf + (it - 1) * 8, rnbuf + it * 8, pc, pa);
        float* t = pc; pc = pa; pa = t;
      }
      k_cg2a<<<cgrid, blk, 0, stream>>>(xbuf, rbuf, pc, Bp,
          rnbuf + it * 8, denbuf + it * 8, rnbuf + (it + 1) * 8, nullptr);
    }
  }

  // ================= outer 1 =================
  // mask phase: hi/lo pre-split planes; KS=3 mconv at NT=2/z=4 (r20)
  fused_fwd<2><<<dim3(64, 1, 8), blk, 0, stream>>>(
      xbuf, m1_0, m1_1, nullptr, t8h, t8l, nullptr, nullptr, nullptr, nullptr, nullptr);
  mconv<9, 8, 1, 81, 21, 16, 4, 4, 8, 4><<<dim3(64, 8, 2), blk, 0, stream>>>(
      t8h, t8l, wAm_hi, wAm_lo, P1h, P1l, nullptr, c_sp1, nullptr, 0, 0);
  for (int bc = 0; bc < 2; ++bc) {
    mconv<3, 128, 16, 9, 3, 16, 4, 2, 8, 4><<<dim3(64, 4, 4), blk, 0, stream>>>(
        P1h, P1l, wC2_hi, wC2_lo, P2h, P2l, nullptr, c_sp2, nullptr, bc * 4, 0);
    mconv<3, 128, 16, 9, 3, 16, 4, 2, 8, 2><<<dim3(64, 4, 4), blk, 0, stream>>>(
        P2h, P2l, wC3_hi, wC3_lo, nullptr, nullptr, mask_c, c_sp3, scal, 0, bc * 4);
  }

  // rn slots 7..13, den slots 6 (scratch) + 7..12
  BtB(xbuf, Bp, denbuf + 6 * 8, nullptr, nullptr, nullptr, nullptr);
  k_cg0p<<<cgrid, blk, 0, stream>>>(bimg, Bp, rbuf, pbuf, rnbuf + 7 * 8);
  {
    float* pc = pbuf;
    float* pa = pbuf2;
    for (int it = 0; it < 6; ++it) {
      if (it == 0) {
        BtB(pc, Bp, denbuf + (7 + it) * 8, nullptr, nullptr, nullptr, nullptr);
      } else {
        BtB(nullptr, Bp, denbuf + (7 + it) * 8,
            rnbuf + (7 + it - 1) * 8, rnbuf + (7 + it) * 8, pc, pa);
        float* t = pc; pc = pa; pa = t;
      }
      float* xout = (it == 5) ? (float*)d_out : nullptr;
      k_cg2a<<<cgrid, blk, 0, stream>>>(xbuf, rbuf, pc, Bp,
          rnbuf + (7 + it) * 8, denbuf + (7 + it) * 8, rnbuf + (8 + it) * 8, xout);
    }
  }
}

// Round 11
// 3007.789 us; speedup vs baseline: 1.3235x; 1.3235x over previous
//
#include <hip/hip_runtime.h>

#define HW 16384
#define BATCH 8

typedef unsigned short u16;
typedef __attribute__((ext_vector_type(8))) short bfrag;   // 8 bf16 in 4 VGPRs
typedef __attribute__((ext_vector_type(4))) float ffrag;   // MFMA accumulator
typedef __attribute__((ext_vector_type(4))) float f4v;

// ---------------------------------------------------------------------------
__device__ __forceinline__ u16 f2bf(float f) {
  unsigned int u = __float_as_uint(f);
  u += 0x7FFFu + ((u >> 16) & 1u);
  return (u16)(u >> 16);
}
__device__ __forceinline__ float bf2f(u16 h) {
  return __uint_as_float(((unsigned int)h) << 16);
}
__device__ __forceinline__ ffrag mfma16(bfrag a, bfrag b, ffrag c) {
  return __builtin_amdgcn_mfma_f32_16x16x32_bf16(a, b, c, 0, 0, 0);
}

__device__ __forceinline__ float spline_eval(float x, const float* __restrict__ c,
                                             int K, float xmin, float xmax) {
  float step = (xmax - xmin) / (float)(K - 1);
  float t = (x - xmin) / step;
  float fidx = floorf(t);
  fidx = fminf(fmaxf(fidx, 0.0f), (float)(K - 2));
  int idx = (int)fidx;
  float frac = t - fidx;
  return c[idx] * (1.0f - frac) + c[idx + 1] * frac;
}
__device__ __forceinline__ float spline31(float x, const float* __restrict__ c) {
  float t = x * 10.0f;
  float fi = floorf(t);
  fi = fminf(fmaxf(fi, 0.0f), 29.0f);
  int i = (int)fi;
  float fr = t - fi;
  return c[i] * (1.0f - fr) + c[i + 1] * fr;
}

// ---------------------------------------------------------------------------
// Weight prep: OIHW fp32 -> MFMA B-fragment order, bf16 hi/lo planes. (r4-r11)
// ---------------------------------------------------------------------------
template<int KS, int CIW, int CO, int NTT, int NSLICE, int TAPS, int CHUNKS, bool TR>
__global__ void k_prepw(const float* __restrict__ W, u16* __restrict__ hi,
                        u16* __restrict__ lo) {
  int gid = blockIdx.x * 256 + threadIdx.x;
  const int total = NSLICE * CHUNKS * NTT * 64;
  if (gid >= total) return;
  int L = gid & 63;
  int rest = gid >> 6;
  int ntg = rest % NTT; rest /= NTT;
  int ch = rest % CHUNKS;
  int sl = rest / CHUNKS;
  int q = L >> 4, n = L & 15;
  int tap = ch * 4 + q;
  int co = ntg * 16 + n;
  int dh = tap / KS, dw = tap - dh * KS;
  for (int j = 0; j < 8; ++j) {
    int ci = sl * 8 + j;
    float v = 0.0f;
    if (tap < TAPS && co < CO) {
      if (TR)
        v = W[(((size_t)ci * CO + co) * KS + (KS - 1 - dh)) * KS + (KS - 1 - dw)];
      else
        v = W[(((size_t)co * CIW + ci) * KS + dh) * KS + dw];
    }
    u16 h = f2bf(v);
    hi[(size_t)gid * 8 + j] = h;
    lo[(size_t)gid * 8 + j] = f2bf(v - bf2f(h));
  }
}

// ---------------------------------------------------------------------------
// bconv (r6-verified core + KSPLIT; plain staging — dbuf regressed in r14):
// LDS-staged 1-term bf16 MFMA conv.
// KSPLIT>1: blockIdx.z = K-slice group (co-group fixed 0), partial fp32 out.
// EPI 3: v*m^2 -> slice-major bf16 (128ch)
// EPI 5: partial fp32, co<8 -> part[(bz*BATCH+bb)*HW + px]*8 + co
// ---------------------------------------------------------------------------
template<int KS, int SLICES, int TAPS, int CHUNKS, int NT, int NTT, int KSPLIT, int EPI>
__global__ __launch_bounds__(256) void bconv(
    const u16* __restrict__ in, const u16* __restrict__ wHi,
    float* __restrict__ outF, u16* __restrict__ outBf,
    const u16* __restrict__ mskc)
{
  constexpr int P   = KS / 2;
  constexpr int IW  = 16 + 2 * P;
  constexpr int IH  = 16 + 2 * P;
  constexpr int SPB = SLICES / KSPLIT;

  __shared__ __align__(16) u16 sA[IH * IW * 8];

  const int tid = threadIdx.x;
  const int wv  = tid >> 6;
  const int L   = tid & 63;
  const int q   = L >> 4;
  const int n16 = L & 15;

  const int tx = blockIdx.x & 7, ty = blockIdx.x >> 3;
  const int w0 = tx * 16, h0 = ty * 16;
  const int bb = blockIdx.y;
  const int bz = blockIdx.z;
  const int slc0 = (KSPLIT > 1) ? bz * SPB : 0;
  const int cog  = (KSPLIT > 1) ? 0 : bz;

  ffrag acc[4][NT];
#pragma unroll
  for (int i = 0; i < 4; ++i)
#pragma unroll
    for (int t = 0; t < NT; ++t) acc[i][t] = (ffrag)0.0f;

  for (int s = 0; s < SPB; ++s) {
    const int slc = slc0 + s;
    __syncthreads();
    for (int e = tid; e < IH * IW; e += 256) {
      int ih = e / IW, iw = e - ih * IW;
      int gh = h0 + ih - P, gw = w0 + iw - P;
      f4v v = (f4v)0.0f;
      if (gh >= 0 && gh < 128 && gw >= 0 && gw < 128)
        v = *(const f4v*)(in + (((size_t)(bb * SLICES + slc) * HW) + gh * 128 + gw) * 8);
      *(f4v*)(sA + (size_t)e * 8) = v;
    }
    __syncthreads();

    const u16* wS = wHi + (size_t)slc * CHUNKS * NTT * 512;
    for (int ch = 0; ch < CHUNKS; ++ch) {
      int tap = ch * 4 + q;
      int dh = 0, dw = 0;
      if (tap < TAPS) { dh = tap / KS; dw = tap - dh * KS; }
      int toff = dh * IW + dw;
      bfrag A[4];
#pragma unroll
      for (int i = 0; i < 4; ++i)
        A[i] = *(const bfrag*)(sA + ((wv * 4 + i) * IW + n16 + toff) * 8);
#pragma unroll
      for (int t = 0; t < NT; ++t) {
        bfrag B = *(const bfrag*)(wS + ((size_t)ch * NTT + cog * NT + t) * 512 + L * 8);
#pragma unroll
        for (int i = 0; i < 4; ++i) acc[i][t] = mfma16(A[i], B, acc[i][t]);
      }
    }
  }

#pragma unroll
  for (int i = 0; i < 4; ++i) {
    const int h = h0 + wv * 4 + i;
#pragma unroll
    for (int t = 0; t < NT; ++t) {
      const int co = cog * (NT * 16) + t * 16 + n16;
#pragma unroll
      for (int r = 0; r < 4; ++r) {
        const int w = w0 + q * 4 + r;
        float v = acc[i][t][r];
        if (EPI == 3) {
          size_t o = (((size_t)(bb * 16 + (co >> 3)) * HW) + h * 128 + w) * 8 + (co & 7);
          float m = bf2f(mskc[o]);
          outBf[o] = f2bf(v * m * m);
        } else if (EPI == 5) {
          if (n16 < 8)
            outF[(((size_t)bz * BATCH + bb) * HW + h * 128 + w) * 8 + n16] = v;
        }
      }
    }
  }
}

// ---------------------------------------------------------------------------
// mconv (r14: TH=16, pre-split bf16 hi/lo input, double-buffered staging;
// r20: KS=3 instances at NT=2/z=4 — A/B vs r19 runs THIS round, clean).
// EPI 4: spline31(|v|) -> hi/lo bf16 slice-major planes
// EPI 2: clip spline -> mask_c bf16
// ---------------------------------------------------------------------------
template<int KS, int CIN, int NSLICE, int TAPS, int CHUNKS,
         int TH, int MTW, int NT, int NTT, int EPI>
__global__ __launch_bounds__(256) void mconv(
    const u16* __restrict__ inH, const u16* __restrict__ inL,
    const u16* __restrict__ wHi, const u16* __restrict__ wLo,
    u16* __restrict__ outH, u16* __restrict__ outL,
    u16* __restrict__ outBf,
    const float* __restrict__ sp, const float* __restrict__ sl,
    int binOfs, int boutOfs)
{
  constexpr int P  = KS / 2;
  constexpr int IW = 16 + 2 * P;
  constexpr int IH = TH + 2 * P;
  constexpr int NE = (IH * IW + 255) / 256;

  __shared__ __align__(16) u16 sHi[IH * IW * 8];
  __shared__ __align__(16) u16 sLo[IH * IW * 8];

  const int tid = threadIdx.x;
  const int wv  = tid >> 6;
  const int L   = tid & 63;
  const int q   = L >> 4;
  const int n16 = L & 15;

  const int tx = blockIdx.x & 7;
  const int ty = blockIdx.x >> 3;
  const int w0 = tx * 16, h0 = ty * TH;
  const int bin  = (int)blockIdx.y + binOfs;
  const int bout = (int)blockIdx.y + boutOfs;
  const int bz = blockIdx.z;

  ffrag acc[MTW][NT];
#pragma unroll
  for (int i = 0; i < MTW; ++i)
#pragma unroll
    for (int t = 0; t < NT; ++t) acc[i][t] = (ffrag)0.0f;

  auto ldslice = [&](int slc, f4v* ph, f4v* pl) {
#pragma unroll
    for (int k = 0; k < NE; ++k) {
      int e = tid + k * 256;
      ph[k] = (f4v)0.0f;
      pl[k] = (f4v)0.0f;
      if (e < IH * IW) {
        int ih = e / IW, iw = e - ih * IW;
        int gh = h0 + ih - P, gw = w0 + iw - P;
        if (gh >= 0 && gh < 128 && gw >= 0 && gw < 128) {
          size_t o = (((size_t)(bin * NSLICE + slc) * HW) + gh * 128 + gw) * 8;
          ph[k] = *(const f4v*)(inH + o);
          pl[k] = *(const f4v*)(inL + o);
        }
      }
    }
  };

  f4v rh[NE], rl[NE];
  ldslice(0, rh, rl);

  for (int slc = 0; slc < NSLICE; ++slc) {
    __syncthreads();
#pragma unroll
    for (int k = 0; k < NE; ++k) {
      int e = tid + k * 256;
      if (e < IH * IW) {
        *(f4v*)(sHi + (size_t)e * 8) = rh[k];
        *(f4v*)(sLo + (size_t)e * 8) = rl[k];
      }
    }
    f4v nh[NE], nl[NE];
    if (slc + 1 < NSLICE) {
      ldslice(slc + 1, nh, nl);
    } else {
#pragma unroll
      for (int k = 0; k < NE; ++k) { nh[k] = (f4v)0.0f; nl[k] = (f4v)0.0f; }
    }
    __syncthreads();

    const u16* wHs = wHi + (size_t)slc * CHUNKS * NTT * 512;
    const u16* wLs = wLo + (size_t)slc * CHUNKS * NTT * 512;
    for (int ch = 0; ch < CHUNKS; ++ch) {
      int tap = ch * 4 + q;
      int dh = tap / KS;
      int dw = tap - dh * KS;
      int toff = (tap < TAPS) ? (dh * IW + dw) : 0;
      bfrag Ah[MTW], Al[MTW];
#pragma unroll
      for (int i = 0; i < MTW; ++i) {
        int a8 = ((wv * MTW + i) * IW + n16 + toff) * 8;
        Ah[i] = *(const bfrag*)(sHi + a8);
        Al[i] = *(const bfrag*)(sLo + a8);
      }
#pragma unroll
      for (int t = 0; t < NT; ++t) {
        size_t off = ((size_t)ch * NTT + bz * NT + t) * 512 + L * 8;
        bfrag Bh = *(const bfrag*)(wHs + off);
        bfrag Bl = *(const bfrag*)(wLs + off);
#pragma unroll
        for (int i = 0; i < MTW; ++i) {
          acc[i][t] = mfma16(Ah[i], Bh, acc[i][t]);
          acc[i][t] = mfma16(Ah[i], Bl, acc[i][t]);
          acc[i][t] = mfma16(Al[i], Bh, acc[i][t]);
        }
      }
    }
#pragma unroll
    for (int k = 0; k < NE; ++k) { rh[k] = nh[k]; rl[k] = nl[k]; }
  }

#pragma unroll
  for (int i = 0; i < MTW; ++i) {
    const int h = h0 + wv * MTW + i;
#pragma unroll
    for (int t = 0; t < NT; ++t) {
      const int co = bz * (NT * 16) + t * 16 + n16;
#pragma unroll
      for (int r = 0; r < 4; ++r) {
        const int w = w0 + q * 4 + r;
        float v = acc[i][t][r];
        if (EPI == 4) {
          float x = spline31(fabsf(v), sp);
          u16 hb = f2bf(x);
          size_t o = (((size_t)(bout * 16 + (co >> 3)) * HW) + h * 128 + w) * 8 + (co & 7);
          outH[o] = hb;
          outL[o] = f2bf(x - bf2f(hb));
        } else if (EPI == 2) {
          float s = sl[bout * 128 + co];
          float x = spline31(s * fabsf(v), sp);
          x = fminf(fmaxf(x, 0.01f), 1.0f);
          size_t o = (((size_t)(bout * 16 + (co >> 3)) * HW) + h * 128 + w) * 8 + (co & 7);
          outBf[o] = f2bf(x);
        }
      }
    }
  }
}

// ---------------------------------------------------------------------------
// fused forward 1->4->8 (r21: REVERTED to r19 form — r20's co-loop split sent
// VGPR 176->256 and ~450 MB/call spill traffic; r17's bounds-hint forced
// VGPR 84 with the same spill signature. VGPR=176 @ 8 waves/CU is this
// kernel's operating point — do not touch register pressure again).
// r19: CG p-update fused into staging (rnp != nullptr).
// OUT 0: fp32 NHWC8 | OUT 1: bf16 8ch | OUT 2: bf16 hi/lo 8ch planes
// ---------------------------------------------------------------------------
template<int OUT>
__global__ __launch_bounds__(256) void fused_fwd(
    const float* __restrict__ in, const float* __restrict__ wA,
    const float* __restrict__ wB, float* __restrict__ outF,
    u16* __restrict__ outBf, u16* __restrict__ outLo,
    const float* __restrict__ rr, const float* __restrict__ pold,
    float* __restrict__ pnew, const float* __restrict__ rnp,
    const float* __restrict__ rnn)
{
  __shared__ float sX[32 * 32];
  __shared__ float sT4[4][24 * 25];
  __shared__ float sWA[81 * 4];
  __shared__ float sWB[4 * 81 * 8];

  const int tid = threadIdx.x;
  const int b   = blockIdx.z;
  const int h0  = (blockIdx.x >> 3) * 16;
  const int w0  = (blockIdx.x & 7) * 16;

  const bool doP = (rnp != nullptr);
  float beta = 0.0f;
  if (doP) {
    float rnb = rnp[b];
    beta = (rnb > 1e-6f) ? (rnn[b] / rnb) : 0.0f;
  }

  for (int e = tid; e < 1024; e += 256) {
    int r = e >> 5, c = e & 31;
    int gh = h0 - 8 + r, gw = w0 - 8 + c;
    float v = 0.0f;
    if (gh >= 0 && gh < 128 && gw >= 0 && gw < 128) {
      size_t idx = (size_t)b * HW + gh * 128 + gw;
      if (doP) {
        v = rr[idx] + beta * pold[idx];
        if (r >= 8 && r < 24 && c >= 8 && c < 24) pnew[idx] = v;
      } else {
        v = in[idx];
      }
    }
    sX[e] = v;
  }
  for (int e = tid; e < 324; e += 256) {
    int co = e & 3, tap = e >> 2;
    sWA[tap * 4 + co] = wA[co * 81 + tap];
  }
  for (int e = tid; e < 2592; e += 256) {
    int co = e & 7;
    int rest = e >> 3;
    int tap = rest % 81, ci = rest / 81;
    sWB[(ci * 81 + tap) * 8 + co] = wB[((size_t)co * 4 + ci) * 81 + tap];
  }
  __syncthreads();

  for (int e = tid; e < 576; e += 256) {
    int r = e / 24, c = e - (e / 24) * 24;
    int gh = h0 - 4 + r, gw = w0 - 4 + c;
    float a0 = 0.0f, a1 = 0.0f, a2 = 0.0f, a3 = 0.0f;
    if (gh >= 0 && gh < 128 && gw >= 0 && gw < 128) {
      for (int kh = 0; kh < 9; ++kh) {
#pragma unroll
        for (int kw = 0; kw < 9; ++kw) {
          float x = sX[(r + kh) * 32 + (c + kw)];
          const float* wp = &sWA[(kh * 9 + kw) * 4];
          a0 += x * wp[0]; a1 += x * wp[1]; a2 += x * wp[2]; a3 += x * wp[3];
        }
      }
    }
    sT4[0][r * 25 + c] = a0;
    sT4[1][r * 25 + c] = a1;
    sT4[2][r * 25 + c] = a2;
    sT4[3][r * 25 + c] = a3;
  }
  __syncthreads();

  const int c  = tid & 15;
  const int r0 = tid >> 4;
  float acc[8];
#pragma unroll
  for (int co = 0; co < 8; ++co) acc[co] = 0.0f;

  for (int ci = 0; ci < 4; ++ci) {
    const float* t4c = sT4[ci];
    for (int kh = 0; kh < 9; ++kh) {
#pragma unroll
      for (int kw = 0; kw < 9; ++kw) {
        float x0 = t4c[(r0 + kh) * 25 + c + kw];
        const float* wp = &sWB[(ci * 81 + kh * 9 + kw) * 8];
#pragma unroll
        for (int co = 0; co < 8; ++co) acc[co] += x0 * wp[co];
      }
    }
  }

  {
    const int h = h0 + r0;
    const int w = w0 + c;
#pragma unroll
    for (int co = 0; co < 8; ++co) {
      float v = acc[co];
      if (OUT == 0) {
        outF[(((size_t)b * 128 + h) * 128 + w) * 8 + co] = v;
      } else if (OUT == 1) {
        outBf[((size_t)b * HW + h * 128 + w) * 8 + co] = f2bf(v);
      } else {
        u16 hb = f2bf(v);
        size_t o = ((size_t)b * HW + h * 128 + w) * 8 + co;
        outBf[o] = hb;
        outLo[o] = f2bf(v - bf2f(hb));
      }
    }
  }
}

// ---------------------------------------------------------------------------
// fused tail (r17: 384 threads — middle stage 288 items single-pass,
// occupancy 8 -> 12 waves/CU; r6-vs-r8 A/B says within-noise — kept).
// 8 ->(9x9 t-conv) 4 ->(9x9 t-conv) 1, then (vin + lam*v)/(1+lam);
// per-block <vin, vout> partial -> atomicAdd den[b]. grid (64,1,8).
// ---------------------------------------------------------------------------
__global__ __launch_bounds__(384) void fused_tail(
    const float* __restrict__ part, const float* __restrict__ w11,
    const float* __restrict__ w10, const float* __restrict__ vin,
    const float* __restrict__ lam, float* __restrict__ vout,
    float* __restrict__ den)
{
  __shared__ float sX[8][1057];
  __shared__ float sT4[4][24 * 25];
  __shared__ float sW1[8 * 81 * 4];
  __shared__ float sW0[4 * 81];
  __shared__ float sRed[256];

  const int tid = threadIdx.x;
  const int b   = blockIdx.z;
  const int h0  = (blockIdx.x >> 3) * 16;
  const int w0  = (blockIdx.x & 7) * 16;

  for (int e = tid; e < 1024; e += 384) {
    int r = e >> 5, c = e & 31;
    int gh = h0 - 8 + r, gw = w0 - 8 + c;
    float v[8];
#pragma unroll
    for (int ci = 0; ci < 8; ++ci) v[ci] = 0.0f;
    if (gh >= 0 && gh < 128 && gw >= 0 && gw < 128) {
      const float* s = part + ((size_t)b * HW + gh * 128 + gw) * 8;
#pragma unroll
      for (int z = 0; z < 4; ++z) {
        f4v a  = *(const f4v*)(s + (size_t)z * 1048576);
        f4v b2 = *(const f4v*)(s + (size_t)z * 1048576 + 4);
        v[0] += a[0]; v[1] += a[1]; v[2] += a[2]; v[3] += a[3];
        v[4] += b2[0]; v[5] += b2[1]; v[6] += b2[2]; v[7] += b2[3];
      }
    }
#pragma unroll
    for (int ci = 0; ci < 8; ++ci) sX[ci][r * 33 + c] = v[ci];
  }
  for (int e = tid; e < 2592; e += 384) {
    int co = e & 3;
    int rest = e >> 2;
    int tap = rest % 81, ci = rest / 81;
    sW1[(ci * 81 + tap) * 4 + co] = w11[(size_t)(ci * 4 + co) * 81 + (80 - tap)];
  }
  for (int e = tid; e < 324; e += 384) {
    int tap = e % 81, ci = e / 81;
    sW0[ci * 81 + tap] = w10[(size_t)ci * 81 + (80 - tap)];
  }
  __syncthreads();

  for (int e = tid; e < 288; e += 384) {
    int r = e / 12, c2 = (e - r * 12) * 2;
    int gh = h0 - 4 + r;
    int gw0 = w0 - 4 + c2;
    float a0[4] = {0, 0, 0, 0}, a1[4] = {0, 0, 0, 0};
    for (int ci = 0; ci < 8; ++ci) {
      for (int kh = 0; kh < 9; ++kh) {
        const float* xb = &sX[ci][(r + kh) * 33 + c2];
#pragma unroll
        for (int kw = 0; kw < 9; ++kw) {
          float x0 = xb[kw], x1 = xb[kw + 1];
          const float* wp = &sW1[(ci * 81 + kh * 9 + kw) * 4];
#pragma unroll
          for (int co = 0; co < 4; ++co) {
            a0[co] += x0 * wp[co];
            a1[co] += x1 * wp[co];
          }
        }
      }
    }
    bool in0 = (gh >= 0 && gh < 128 && gw0 >= 0 && gw0 < 128);
    bool in1 = (gh >= 0 && gh < 128 && (gw0 + 1) >= 0 && (gw0 + 1) < 128);
#pragma unroll
    for (int co = 0; co < 4; ++co) {
      sT4[co][r * 25 + c2]     = in0 ? a0[co] : 0.0f;
      sT4[co][r * 25 + c2 + 1] = in1 ? a1[co] : 0.0f;
    }
  }
  __syncthreads();

  if (tid < 256) {
    int r = tid >> 4, c = tid & 15;
    float acc = 0.0f;
    for (int ci = 0; ci < 4; ++ci) {
      for (int kh = 0; kh < 9; ++kh) {
        const float* xb = &sT4[ci][(r + kh) * 25 + c];
        const float* wp = &sW0[ci * 81 + kh * 9];
#pragma unroll
        for (int kw = 0; kw < 9; ++kw) acc += xb[kw] * wp[kw];
      }
    }
    size_t o = (size_t)b * HW + (h0 + r) * 128 + (w0 + c);
    float l = lam[b];
    float vi = vin[o];
    float res = (vi + l * acc) / (1.0f + l);
    vout[o] = res;
    sRed[tid] = vi * res;
  }
  __syncthreads();
  for (int st = 128; st > 0; st >>= 1) {
    if (tid < st) sRed[tid] += sRed[tid + st];
    __syncthreads();
  }
  if (tid == 0) atomicAdd(&den[b], sRed[0]);
}

// ---------------------------------------------------------------------------
// helpers
// ---------------------------------------------------------------------------
__global__ void k_scalars(const float* __restrict__ sigma, const float* __restrict__ c_lam,
                          const float* __restrict__ c_scal, float* __restrict__ lam,
                          float* __restrict__ scal) {
  int tid = threadIdx.x;
  if (tid < BATCH) lam[tid] = spline_eval(sigma[tid], c_lam, 53, -1.0f, 51.0f);
  for (int j = tid; j < BATCH * 128; j += 256) {
    int b = j >> 7, chn = j & 127;
    float s = sigma[b];
    scal[j] = expf(spline_eval(s, c_scal + chn * 14, 14, -1.0f, 51.0f)) / (s + 1e-5f);
  }
}

// r16: also zeroes the 256-float CG scalar-slot region (rnbuf+denbuf)
__global__ void k_binit(const float* __restrict__ y, const float* __restrict__ lam,
                        float* __restrict__ bimg, float* __restrict__ x,
                        float* __restrict__ cgscal) {
  int i = blockIdx.x * 256 + threadIdx.x;
  int b = i >> 14;
  bimg[i] = y[i] / (1.0f + lam[b]);
  x[i] = 0.0f;
  if (blockIdx.x == 0) cgscal[threadIdx.x] = 0.0f;
}

// mask for c_k = 0 (bit-exact, r11-verified)
__global__ void k_fillmask(const float* __restrict__ c_sp3, u16* __restrict__ mask_c) {
  u16 hv = f2bf(fminf(fmaxf(c_sp3[0], 0.01f), 1.0f));
  u16 tmp[8];
#pragma unroll
  for (int j = 0; j < 8; ++j) tmp[j] = hv;
  size_t i = ((size_t)blockIdx.x * 256 + threadIdx.x) * 8;
  *(f4v*)(mask_c + i) = *(const f4v*)tmp;
}

// ---------------------------------------------------------------------------
// r16 parallel CG kernels. Per-iteration rn/den slots (pre-zeroed) remove all
// scalar-rotation races; grid (32,8) = 256 blocks. r19: k_cg2b removed —
// the p-update is fused into the next BtB's fused_fwd staging.
// ---------------------------------------------------------------------------
// r = p = bimg [- Bp]; atomicAdd <r,r> into rnout[b].
__global__ __launch_bounds__(256) void k_cg0p(
    const float* __restrict__ bimg, const float* __restrict__ Bp,
    float* __restrict__ r, float* __restrict__ p, float* __restrict__ rnout) {
  __shared__ float s[256];
  int b = blockIdx.y;
  size_t base = ((size_t)b << 14) + (size_t)blockIdx.x * 512;
  float local = 0.0f;
  for (int i = threadIdx.x; i < 512; i += 256) {
    float v = bimg[base + i];
    if (Bp) v -= Bp[base + i];
    r[base + i] = v;
    p[base + i] = v;
    local += v * v;
  }
  s[threadIdx.x] = local;
  __syncthreads();
  for (int st = 128; st > 0; st >>= 1) {
    if (threadIdx.x < st) s[threadIdx.x] += s[threadIdx.x + st];
    __syncthreads();
  }
  if (threadIdx.x == 0) atomicAdd(&rnout[b], s[0]);
}

// alpha = rnp/deng (guarded); x += alpha p (opt xout); r -= alpha Bp;
// atomicAdd <r',r'> into rnn[b].
__global__ __launch_bounds__(256) void k_cg2a(
    float* __restrict__ x, float* __restrict__ r, const float* __restrict__ p,
    const float* __restrict__ Bp, const float* __restrict__ rnp,
    const float* __restrict__ deng, float* __restrict__ rnn,
    float* __restrict__ xout) {
  __shared__ float s[256];
  int b = blockIdx.y;
  size_t base = ((size_t)b << 14) + (size_t)blockIdx.x * 512;
  float rnb = rnp[b];
  bool act = rnb > 1e-6f;
  float alpha = act ? rnb / deng[b] : 0.0f;
  float local = 0.0f;
  for (int i = threadIdx.x; i < 512; i += 256) {
    float pv = p[base + i];
    float xv = x[base + i] + alpha * pv;
    x[base + i] = xv;
    if (xout) xout[base + i] = xv;
    float rr = r[base + i] - alpha * Bp[base + i];
    r[base + i] = rr;
    local += rr * rr;
  }
  s[threadIdx.x] = local;
  __syncthreads();
  for (int st = 128; st > 0; st >>= 1) {
    if (threadIdx.x < st) s[threadIdx.x] += s[threadIdx.x + st];
    __syncthreads();
  }
  if (threadIdx.x == 0) atomicAdd(&rnn[b], s[0]);
}

// ---------------------------------------------------------------------------
extern "C" void kernel_launch(void* const* d_in, const int* in_sizes, int n_in_,
                              void* d_out, int out_size, void* d_ws, size_t ws_size,
                              hipStream_t stream) {
  const float* y      = (const float*)d_in[0];
  const float* sigma  = (const float*)d_in[1];
  const float* w1_0   = (const float*)d_in[2];
  const float* w1_1   = (const float*)d_in[3];
  const float* w1_2   = (const float*)d_in[4];
  const float* m1_0   = (const float*)d_in[5];
  const float* m1_1   = (const float*)d_in[6];
  const float* m1_2   = (const float*)d_in[7];
  const float* m2_w   = (const float*)d_in[8];
  const float* m3_w   = (const float*)d_in[9];
  const float* c_sp1  = (const float*)d_in[10];
  const float* c_sp2  = (const float*)d_in[11];
  const float* c_sp3  = (const float*)d_in[12];
  const float* c_lam  = (const float*)d_in[13];
  const float* c_scal = (const float*)d_in[14];
  // n_out = 2, n_in = 6 fixed by setup_inputs

  char* cur = (char*)d_ws;
  auto alloc = [&](size_t bytes) {
    char* p = cur;
    cur += (bytes + 255) & ~(size_t)255;
    return p;
  };

  // weight fragments (~3 MB)
  u16* wA_hi  = (u16*)alloc(86016 * 2);
  u16* wA_lo  = (u16*)alloc(86016 * 2);
  u16* wAm_hi = (u16*)alloc(86016 * 2);
  u16* wAm_lo = (u16*)alloc(86016 * 2);
  u16* wB_hi  = (u16*)alloc(172032 * 2);
  u16* wB_lo  = (u16*)alloc(172032 * 2);
  u16* wC2_hi = (u16*)alloc(196608 * 2);
  u16* wC2_lo = (u16*)alloc(196608 * 2);
  u16* wC3_hi = (u16*)alloc(196608 * 2);
  u16* wC3_lo = (u16*)alloc(196608 * 2);

  // region1 (67.1 MB): mask phase = P1 hi/lo bf16 planes; CG = big2c bf16
  char* region1 = alloc((size_t)16777216 * 4);
  u16* P1h   = (u16*)region1;
  u16* P1l   = (u16*)(region1 + (size_t)16777216 * 2);
  u16* big2c = (u16*)region1;
  // mask_c bf16 slice-major (33.5 MB)
  u16* mask_c = (u16*)alloc((size_t)16777216 * 2);
  // region2 (33.6 MB): mask = P2 hi/lo planes x4 batches; CG = part fp32
  char* region2 = alloc((size_t)4 * 128 * 128 * 128 * 4);
  u16*   P2h  = (u16*)region2;
  u16*   P2l  = (u16*)(region2 + (size_t)8388608 * 2);
  float* part = (float*)region2;                          // 4 x 1048576 fp32
  // region3 (4.2 MB): mask = t8 hi/lo planes; CG = t8c bf16 slice-major
  char* region3 = alloc((size_t)1048576 * 4);
  u16* t8h = (u16*)region3;
  u16* t8l = (u16*)(region3 + (size_t)1048576 * 2);
  u16* t8c = (u16*)region3;

  float* bimg  = (float*)alloc(131072 * 4);
  float* xbuf  = (float*)alloc(131072 * 4);
  float* rbuf  = (float*)alloc(131072 * 4);
  float* pbuf  = (float*)alloc(131072 * 4);
  float* pbuf2 = (float*)alloc(131072 * 4);   // r19: p ping-pong partner
  float* Bp    = (float*)alloc(131072 * 4);
  float* lam   = (float*)alloc(8 * 4);
  float* scal  = (float*)alloc(1024 * 4);
  // r16: CG scalar slots — rnbuf[16][8] then denbuf[16][8], zeroed in k_binit
  float* cgscal = (float*)alloc(256 * 4);
  float* rnbuf  = cgscal;
  float* denbuf = cgscal + 128;
  // total ~145 MB

  const dim3 blk(256);
  const dim3 blk384(384);
  const dim3 cgrid(32, 8);

  k_prepw<9, 8, 128, 8, 1, 81, 21, false><<<dim3(42), blk, 0, stream>>>(w1_2, wA_hi, wA_lo);
  k_prepw<9, 8, 128, 8, 1, 81, 21, false><<<dim3(42), blk, 0, stream>>>(m1_2, wAm_hi, wAm_lo);
  k_prepw<9, 8, 8, 1, 16, 81, 21, true><<<dim3(84), blk, 0, stream>>>(w1_2, wB_hi, wB_lo);
  k_prepw<3, 128, 128, 8, 16, 9, 3, false><<<dim3(96), blk, 0, stream>>>(m2_w, wC2_hi, wC2_lo);
  k_prepw<3, 128, 128, 8, 16, 9, 3, false><<<dim3(96), blk, 0, stream>>>(m3_w, wC3_hi, wC3_lo);

  k_scalars<<<dim3(1), blk, 0, stream>>>(sigma, c_lam, c_scal, lam, scal);
  k_binit<<<dim3(512), blk, 0, stream>>>(y, lam, bimg, xbuf, cgscal);

  // BtB: fused_fwd optionally computes p_new = r + beta*p_old during staging
  // (rnp != nullptr), writing interior pixels to pnew; downstream kernels
  // then consume pnew. vin is used only in plain mode.
  auto BtB = [&](const float* vin, float* vout, float* denp,
                 const float* rnp, const float* rnn,
                 const float* pold, float* pnew) {
    fused_fwd<1><<<dim3(64, 1, 8), blk, 0, stream>>>(
        vin, w1_0, w1_1, nullptr, t8c, nullptr, rbuf, pold, pnew, rnp, rnn);
    bconv<9, 1, 81, 21, 2, 8, 1, 3><<<dim3(64, 8, 4), blk, 0, stream>>>(
        t8c, wA_hi, nullptr, big2c, mask_c);
    bconv<9, 16, 81, 21, 1, 1, 4, 5><<<dim3(64, 8, 4), blk, 0, stream>>>(
        big2c, wB_hi, part, nullptr, nullptr);
    const float* tailvin = rnp ? (const float*)pnew : vin;
    fused_tail<<<dim3(64, 1, 8), blk384, 0, stream>>>(
        part, w1_1, w1_0, tailvin, lam, vout, denp);
  };

  // ================= outer 0: c_k = 0 (algebraic, r11-verified) =============
  // rn slots 0..6, den slots 0..5
  k_fillmask<<<dim3(8192), blk, 0, stream>>>(c_sp3, mask_c);
  k_cg0p<<<cgrid, blk, 0, stream>>>(bimg, nullptr, rbuf, pbuf, rnbuf + 0 * 8);
  {
    float* pc = pbuf;   // current p
    float* pa = pbuf2;  // alternate
    for (int it = 0; it < 6; ++it) {
      if (it == 0) {
        BtB(pc, Bp, denbuf + it * 8, nullptr, nullptr, nullptr, nullptr);
      } else {
        BtB(nullptr, Bp, denbuf + it * 8,
            rnbuf + (it - 1) * 8, rnbuf + it * 8, pc, pa);
        float* t = pc; pc = pa; pa = t;
      }
      k_cg2a<<<cgrid, blk, 0, stream>>>(xbuf, rbuf, pc, Bp,
          rnbuf + it * 8, denbuf + it * 8, rnbuf + (it + 1) * 8, nullptr);
    }
  }

  // ================= outer 1 =================
  // mask phase: hi/lo pre-split planes; KS=3 mconv at NT=2/z=4 (r20, A/B now)
  fused_fwd<2><<<dim3(64, 1, 8), blk, 0, stream>>>(
      xbuf, m1_0, m1_1, nullptr, t8h, t8l, nullptr, nullptr, nullptr, nullptr, nullptr);
  mconv<9, 8, 1, 81, 21, 16, 4, 4, 8, 4><<<dim3(64, 8, 2), blk, 0, stream>>>(
      t8h, t8l, wAm_hi, wAm_lo, P1h, P1l, nullptr, c_sp1, nullptr, 0, 0);
  for (int bc = 0; bc < 2; ++bc) {
    mconv<3, 128, 16, 9, 3, 16, 4, 2, 8, 4><<<dim3(64, 4, 4), blk, 0, stream>>>(
        P1h, P1l, wC2_hi, wC2_lo, P2h, P2l, nullptr, c_sp2, nullptr, bc * 4, 0);
    mconv<3, 128, 16, 9, 3, 16, 4, 2, 8, 2><<<dim3(64, 4, 4), blk, 0, stream>>>(
        P2h, P2l, wC3_hi, wC3_lo, nullptr, nullptr, mask_c, c_sp3, scal, 0, bc * 4);
  }

  // rn slots 7..13, den slots 6 (scratch) + 7..12
  BtB(xbuf, Bp, denbuf + 6 * 8, nullptr, nullptr, nullptr, nullptr);
  k_cg0p<<<cgrid, blk, 0, stream>>>(bimg, Bp, rbuf, pbuf, rnbuf + 7 * 8);
  {
    float* pc = pbuf;
    float* pa = pbuf2;
    for (int it = 0; it < 6; ++it) {
      if (it == 0) {
        BtB(pc, Bp, denbuf + (7 + it) * 8, nullptr, nullptr, nullptr, nullptr);
      } else {
        BtB(nullptr, Bp, denbuf + (7 + it) * 8,
            rnbuf + (7 + it - 1) * 8, rnbuf + (7 + it) * 8, pc, pa);
        float* t = pc; pc = pa; pa = t;
      }
      float* xout = (it == 5) ? (float*)d_out : nullptr;
      k_cg2a<<<cgrid, blk, 0, stream>>>(xbuf, rbuf, pc, Bp,
          rnbuf + (7 + it) * 8, denbuf + (7 + it) * 8, rnbuf + (8 + it) * 8, xout);
    }
  }
}

// Round 12
// 2862.843 us; speedup vs baseline: 1.3906x; 1.0506x over previous
//
#include <hip/hip_runtime.h>

#define HW 16384
#define BATCH 8

typedef unsigned short u16;
typedef __attribute__((ext_vector_type(8))) short bfrag;   // 8 bf16 in 4 VGPRs
typedef __attribute__((ext_vector_type(4))) float ffrag;   // MFMA accumulator
typedef __attribute__((ext_vector_type(4))) float f4v;

// ---------------------------------------------------------------------------
__device__ __forceinline__ u16 f2bf(float f) {
  unsigned int u = __float_as_uint(f);
  u += 0x7FFFu + ((u >> 16) & 1u);
  return (u16)(u >> 16);
}
__device__ __forceinline__ float bf2f(u16 h) {
  return __uint_as_float(((unsigned int)h) << 16);
}
__device__ __forceinline__ ffrag mfma16(bfrag a, bfrag b, ffrag c) {
  return __builtin_amdgcn_mfma_f32_16x16x32_bf16(a, b, c, 0, 0, 0);
}

__device__ __forceinline__ float spline_eval(float x, const float* __restrict__ c,
                                             int K, float xmin, float xmax) {
  float step = (xmax - xmin) / (float)(K - 1);
  float t = (x - xmin) / step;
  float fidx = floorf(t);
  fidx = fminf(fmaxf(fidx, 0.0f), (float)(K - 2));
  int idx = (int)fidx;
  float frac = t - fidx;
  return c[idx] * (1.0f - frac) + c[idx + 1] * frac;
}
__device__ __forceinline__ float spline31(float x, const float* __restrict__ c) {
  float t = x * 10.0f;
  float fi = floorf(t);
  fi = fminf(fmaxf(fi, 0.0f), 29.0f);
  int i = (int)fi;
  float fr = t - fi;
  return c[i] * (1.0f - fr) + c[i + 1] * fr;
}

// ---------------------------------------------------------------------------
// Weight prep: OIHW fp32 -> MFMA B-fragment order, bf16 hi/lo planes. (r4-r11)
// ---------------------------------------------------------------------------
template<int KS, int CIW, int CO, int NTT, int NSLICE, int TAPS, int CHUNKS, bool TR>
__global__ void k_prepw(const float* __restrict__ W, u16* __restrict__ hi,
                        u16* __restrict__ lo) {
  int gid = blockIdx.x * 256 + threadIdx.x;
  const int total = NSLICE * CHUNKS * NTT * 64;
  if (gid >= total) return;
  int L = gid & 63;
  int rest = gid >> 6;
  int ntg = rest % NTT; rest /= NTT;
  int ch = rest % CHUNKS;
  int sl = rest / CHUNKS;
  int q = L >> 4, n = L & 15;
  int tap = ch * 4 + q;
  int co = ntg * 16 + n;
  int dh = tap / KS, dw = tap - dh * KS;
  for (int j = 0; j < 8; ++j) {
    int ci = sl * 8 + j;
    float v = 0.0f;
    if (tap < TAPS && co < CO) {
      if (TR)
        v = W[(((size_t)ci * CO + co) * KS + (KS - 1 - dh)) * KS + (KS - 1 - dw)];
      else
        v = W[(((size_t)co * CIW + ci) * KS + dh) * KS + dw];
    }
    u16 h = f2bf(v);
    hi[(size_t)gid * 8 + j] = h;
    lo[(size_t)gid * 8 + j] = f2bf(v - bf2f(h));
  }
}

// ---------------------------------------------------------------------------
// bconv (r6-verified core + KSPLIT; plain staging — dbuf regressed in r14):
// LDS-staged 1-term bf16 MFMA conv.
// KSPLIT>1: blockIdx.z = K-slice group (co-group fixed 0), partial fp32 out.
// EPI 3: v*m^2 -> slice-major bf16 (128ch)
// EPI 5: partial fp32, co<8 -> part[(bz*BATCH+bb)*HW + px]*8 + co
// ---------------------------------------------------------------------------
template<int KS, int SLICES, int TAPS, int CHUNKS, int NT, int NTT, int KSPLIT, int EPI>
__global__ __launch_bounds__(256) void bconv(
    const u16* __restrict__ in, const u16* __restrict__ wHi,
    float* __restrict__ outF, u16* __restrict__ outBf,
    const u16* __restrict__ mskc)
{
  constexpr int P   = KS / 2;
  constexpr int IW  = 16 + 2 * P;
  constexpr int IH  = 16 + 2 * P;
  constexpr int SPB = SLICES / KSPLIT;

  __shared__ __align__(16) u16 sA[IH * IW * 8];

  const int tid = threadIdx.x;
  const int wv  = tid >> 6;
  const int L   = tid & 63;
  const int q   = L >> 4;
  const int n16 = L & 15;

  const int tx = blockIdx.x & 7, ty = blockIdx.x >> 3;
  const int w0 = tx * 16, h0 = ty * 16;
  const int bb = blockIdx.y;
  const int bz = blockIdx.z;
  const int slc0 = (KSPLIT > 1) ? bz * SPB : 0;
  const int cog  = (KSPLIT > 1) ? 0 : bz;

  ffrag acc[4][NT];
#pragma unroll
  for (int i = 0; i < 4; ++i)
#pragma unroll
    for (int t = 0; t < NT; ++t) acc[i][t] = (ffrag)0.0f;

  for (int s = 0; s < SPB; ++s) {
    const int slc = slc0 + s;
    __syncthreads();
    for (int e = tid; e < IH * IW; e += 256) {
      int ih = e / IW, iw = e - ih * IW;
      int gh = h0 + ih - P, gw = w0 + iw - P;
      f4v v = (f4v)0.0f;
      if (gh >= 0 && gh < 128 && gw >= 0 && gw < 128)
        v = *(const f4v*)(in + (((size_t)(bb * SLICES + slc) * HW) + gh * 128 + gw) * 8);
      *(f4v*)(sA + (size_t)e * 8) = v;
    }
    __syncthreads();

    const u16* wS = wHi + (size_t)slc * CHUNKS * NTT * 512;
    for (int ch = 0; ch < CHUNKS; ++ch) {
      int tap = ch * 4 + q;
      int dh = 0, dw = 0;
      if (tap < TAPS) { dh = tap / KS; dw = tap - dh * KS; }
      int toff = dh * IW + dw;
      bfrag A[4];
#pragma unroll
      for (int i = 0; i < 4; ++i)
        A[i] = *(const bfrag*)(sA + ((wv * 4 + i) * IW + n16 + toff) * 8);
#pragma unroll
      for (int t = 0; t < NT; ++t) {
        bfrag B = *(const bfrag*)(wS + ((size_t)ch * NTT + cog * NT + t) * 512 + L * 8);
#pragma unroll
        for (int i = 0; i < 4; ++i) acc[i][t] = mfma16(A[i], B, acc[i][t]);
      }
    }
  }

#pragma unroll
  for (int i = 0; i < 4; ++i) {
    const int h = h0 + wv * 4 + i;
#pragma unroll
    for (int t = 0; t < NT; ++t) {
      const int co = cog * (NT * 16) + t * 16 + n16;
#pragma unroll
      for (int r = 0; r < 4; ++r) {
        const int w = w0 + q * 4 + r;
        float v = acc[i][t][r];
        if (EPI == 3) {
          size_t o = (((size_t)(bb * 16 + (co >> 3)) * HW) + h * 128 + w) * 8 + (co & 7);
          float m = bf2f(mskc[o]);
          outBf[o] = f2bf(v * m * m);
        } else if (EPI == 5) {
          if (n16 < 8)
            outF[(((size_t)bz * BATCH + bb) * HW + h * 128 + w) * 8 + n16] = v;
        }
      }
    }
  }
}

// ---------------------------------------------------------------------------
// mconv (r22 = r19 champion config RESTORED: TH=16, NT=4, z=2, pre-split bf16
// hi/lo input, double-buffered staging — per-dispatch verified 70 us,
// MfmaUtil 43%, FETCH 39 MB. r20's NT=2/z=4 experiment REGRESSED: 77 us,
// FETCH 85 MB — z-groups duplicate the 16-slice staging halo; staging
// traffic dominates this kernel, so z-splitting is a net loss).
// EPI 4: spline31(|v|) -> hi/lo bf16 slice-major planes
// EPI 2: clip spline -> mask_c bf16
// ---------------------------------------------------------------------------
template<int KS, int CIN, int NSLICE, int TAPS, int CHUNKS,
         int TH, int MTW, int NT, int NTT, int EPI>
__global__ __launch_bounds__(256) void mconv(
    const u16* __restrict__ inH, const u16* __restrict__ inL,
    const u16* __restrict__ wHi, const u16* __restrict__ wLo,
    u16* __restrict__ outH, u16* __restrict__ outL,
    u16* __restrict__ outBf,
    const float* __restrict__ sp, const float* __restrict__ sl,
    int binOfs, int boutOfs)
{
  constexpr int P  = KS / 2;
  constexpr int IW = 16 + 2 * P;
  constexpr int IH = TH + 2 * P;
  constexpr int NE = (IH * IW + 255) / 256;

  __shared__ __align__(16) u16 sHi[IH * IW * 8];
  __shared__ __align__(16) u16 sLo[IH * IW * 8];

  const int tid = threadIdx.x;
  const int wv  = tid >> 6;
  const int L   = tid & 63;
  const int q   = L >> 4;
  const int n16 = L & 15;

  const int tx = blockIdx.x & 7;
  const int ty = blockIdx.x >> 3;
  const int w0 = tx * 16, h0 = ty * TH;
  const int bin  = (int)blockIdx.y + binOfs;
  const int bout = (int)blockIdx.y + boutOfs;
  const int bz = blockIdx.z;

  ffrag acc[MTW][NT];
#pragma unroll
  for (int i = 0; i < MTW; ++i)
#pragma unroll
    for (int t = 0; t < NT; ++t) acc[i][t] = (ffrag)0.0f;

  auto ldslice = [&](int slc, f4v* ph, f4v* pl) {
#pragma unroll
    for (int k = 0; k < NE; ++k) {
      int e = tid + k * 256;
      ph[k] = (f4v)0.0f;
      pl[k] = (f4v)0.0f;
      if (e < IH * IW) {
        int ih = e / IW, iw = e - ih * IW;
        int gh = h0 + ih - P, gw = w0 + iw - P;
        if (gh >= 0 && gh < 128 && gw >= 0 && gw < 128) {
          size_t o = (((size_t)(bin * NSLICE + slc) * HW) + gh * 128 + gw) * 8;
          ph[k] = *(const f4v*)(inH + o);
          pl[k] = *(const f4v*)(inL + o);
        }
      }
    }
  };

  f4v rh[NE], rl[NE];
  ldslice(0, rh, rl);

  for (int slc = 0; slc < NSLICE; ++slc) {
    __syncthreads();
#pragma unroll
    for (int k = 0; k < NE; ++k) {
      int e = tid + k * 256;
      if (e < IH * IW) {
        *(f4v*)(sHi + (size_t)e * 8) = rh[k];
        *(f4v*)(sLo + (size_t)e * 8) = rl[k];
      }
    }
    f4v nh[NE], nl[NE];
    if (slc + 1 < NSLICE) {
      ldslice(slc + 1, nh, nl);
    } else {
#pragma unroll
      for (int k = 0; k < NE; ++k) { nh[k] = (f4v)0.0f; nl[k] = (f4v)0.0f; }
    }
    __syncthreads();

    const u16* wHs = wHi + (size_t)slc * CHUNKS * NTT * 512;
    const u16* wLs = wLo + (size_t)slc * CHUNKS * NTT * 512;
    for (int ch = 0; ch < CHUNKS; ++ch) {
      int tap = ch * 4 + q;
      int dh = tap / KS;
      int dw = tap - dh * KS;
      int toff = (tap < TAPS) ? (dh * IW + dw) : 0;
      bfrag Ah[MTW], Al[MTW];
#pragma unroll
      for (int i = 0; i < MTW; ++i) {
        int a8 = ((wv * MTW + i) * IW + n16 + toff) * 8;
        Ah[i] = *(const bfrag*)(sHi + a8);
        Al[i] = *(const bfrag*)(sLo + a8);
      }
#pragma unroll
      for (int t = 0; t < NT; ++t) {
        size_t off = ((size_t)ch * NTT + bz * NT + t) * 512 + L * 8;
        bfrag Bh = *(const bfrag*)(wHs + off);
        bfrag Bl = *(const bfrag*)(wLs + off);
#pragma unroll
        for (int i = 0; i < MTW; ++i) {
          acc[i][t] = mfma16(Ah[i], Bh, acc[i][t]);
          acc[i][t] = mfma16(Ah[i], Bl, acc[i][t]);
          acc[i][t] = mfma16(Al[i], Bh, acc[i][t]);
        }
      }
    }
#pragma unroll
    for (int k = 0; k < NE; ++k) { rh[k] = nh[k]; rl[k] = nl[k]; }
  }

#pragma unroll
  for (int i = 0; i < MTW; ++i) {
    const int h = h0 + wv * MTW + i;
#pragma unroll
    for (int t = 0; t < NT; ++t) {
      const int co = bz * (NT * 16) + t * 16 + n16;
#pragma unroll
      for (int r = 0; r < 4; ++r) {
        const int w = w0 + q * 4 + r;
        float v = acc[i][t][r];
        if (EPI == 4) {
          float x = spline31(fabsf(v), sp);
          u16 hb = f2bf(x);
          size_t o = (((size_t)(bout * 16 + (co >> 3)) * HW) + h * 128 + w) * 8 + (co & 7);
          outH[o] = hb;
          outL[o] = f2bf(x - bf2f(hb));
        } else if (EPI == 2) {
          float s = sl[bout * 128 + co];
          float x = spline31(s * fabsf(v), sp);
          x = fminf(fmaxf(x, 0.01f), 1.0f);
          size_t o = (((size_t)(bout * 16 + (co >> 3)) * HW) + h * 128 + w) * 8 + (co & 7);
          outBf[o] = f2bf(x);
        }
      }
    }
  }
}

// ---------------------------------------------------------------------------
// fused forward 1->4->8 (r19 form — VGPR 176 @ 8 waves/CU is this kernel's
// operating point; r17 bounds-hint and r20 loop-split both caused massive
// scratch spill. DO NOT touch register pressure here.)
// r19: CG p-update fused into staging (rnp != nullptr).
// OUT 0: fp32 NHWC8 | OUT 1: bf16 8ch | OUT 2: bf16 hi/lo 8ch planes
// ---------------------------------------------------------------------------
template<int OUT>
__global__ __launch_bounds__(256) void fused_fwd(
    const float* __restrict__ in, const float* __restrict__ wA,
    const float* __restrict__ wB, float* __restrict__ outF,
    u16* __restrict__ outBf, u16* __restrict__ outLo,
    const float* __restrict__ rr, const float* __restrict__ pold,
    float* __restrict__ pnew, const float* __restrict__ rnp,
    const float* __restrict__ rnn)
{
  __shared__ float sX[32 * 32];
  __shared__ float sT4[4][24 * 25];
  __shared__ float sWA[81 * 4];
  __shared__ float sWB[4 * 81 * 8];

  const int tid = threadIdx.x;
  const int b   = blockIdx.z;
  const int h0  = (blockIdx.x >> 3) * 16;
  const int w0  = (blockIdx.x & 7) * 16;

  const bool doP = (rnp != nullptr);
  float beta = 0.0f;
  if (doP) {
    float rnb = rnp[b];
    beta = (rnb > 1e-6f) ? (rnn[b] / rnb) : 0.0f;
  }

  for (int e = tid; e < 1024; e += 256) {
    int r = e >> 5, c = e & 31;
    int gh = h0 - 8 + r, gw = w0 - 8 + c;
    float v = 0.0f;
    if (gh >= 0 && gh < 128 && gw >= 0 && gw < 128) {
      size_t idx = (size_t)b * HW + gh * 128 + gw;
      if (doP) {
        v = rr[idx] + beta * pold[idx];
        if (r >= 8 && r < 24 && c >= 8 && c < 24) pnew[idx] = v;
      } else {
        v = in[idx];
      }
    }
    sX[e] = v;
  }
  for (int e = tid; e < 324; e += 256) {
    int co = e & 3, tap = e >> 2;
    sWA[tap * 4 + co] = wA[co * 81 + tap];
  }
  for (int e = tid; e < 2592; e += 256) {
    int co = e & 7;
    int rest = e >> 3;
    int tap = rest % 81, ci = rest / 81;
    sWB[(ci * 81 + tap) * 8 + co] = wB[((size_t)co * 4 + ci) * 81 + tap];
  }
  __syncthreads();

  for (int e = tid; e < 576; e += 256) {
    int r = e / 24, c = e - (e / 24) * 24;
    int gh = h0 - 4 + r, gw = w0 - 4 + c;
    float a0 = 0.0f, a1 = 0.0f, a2 = 0.0f, a3 = 0.0f;
    if (gh >= 0 && gh < 128 && gw >= 0 && gw < 128) {
      for (int kh = 0; kh < 9; ++kh) {
#pragma unroll
        for (int kw = 0; kw < 9; ++kw) {
          float x = sX[(r + kh) * 32 + (c + kw)];
          const float* wp = &sWA[(kh * 9 + kw) * 4];
          a0 += x * wp[0]; a1 += x * wp[1]; a2 += x * wp[2]; a3 += x * wp[3];
        }
      }
    }
    sT4[0][r * 25 + c] = a0;
    sT4[1][r * 25 + c] = a1;
    sT4[2][r * 25 + c] = a2;
    sT4[3][r * 25 + c] = a3;
  }
  __syncthreads();

  const int c  = tid & 15;
  const int r0 = tid >> 4;
  float acc[8];
#pragma unroll
  for (int co = 0; co < 8; ++co) acc[co] = 0.0f;

  for (int ci = 0; ci < 4; ++ci) {
    const float* t4c = sT4[ci];
    for (int kh = 0; kh < 9; ++kh) {
#pragma unroll
      for (int kw = 0; kw < 9; ++kw) {
        float x0 = t4c[(r0 + kh) * 25 + c + kw];
        const float* wp = &sWB[(ci * 81 + kh * 9 + kw) * 8];
#pragma unroll
        for (int co = 0; co < 8; ++co) acc[co] += x0 * wp[co];
      }
    }
  }

  {
    const int h = h0 + r0;
    const int w = w0 + c;
#pragma unroll
    for (int co = 0; co < 8; ++co) {
      float v = acc[co];
      if (OUT == 0) {
        outF[(((size_t)b * 128 + h) * 128 + w) * 8 + co] = v;
      } else if (OUT == 1) {
        outBf[((size_t)b * HW + h * 128 + w) * 8 + co] = f2bf(v);
      } else {
        u16 hb = f2bf(v);
        size_t o = ((size_t)b * HW + h * 128 + w) * 8 + co;
        outBf[o] = hb;
        outLo[o] = f2bf(v - bf2f(hb));
      }
    }
  }
}

// ---------------------------------------------------------------------------
// fused tail (r17: 384 threads — middle stage 288 items single-pass,
// occupancy 8 -> 12 waves/CU; kept).
// 8 ->(9x9 t-conv) 4 ->(9x9 t-conv) 1, then (vin + lam*v)/(1+lam);
// per-block <vin, vout> partial -> atomicAdd den[b]. grid (64,1,8).
// ---------------------------------------------------------------------------
__global__ __launch_bounds__(384) void fused_tail(
    const float* __restrict__ part, const float* __restrict__ w11,
    const float* __restrict__ w10, const float* __restrict__ vin,
    const float* __restrict__ lam, float* __restrict__ vout,
    float* __restrict__ den)
{
  __shared__ float sX[8][1057];
  __shared__ float sT4[4][24 * 25];
  __shared__ float sW1[8 * 81 * 4];
  __shared__ float sW0[4 * 81];
  __shared__ float sRed[256];

  const int tid = threadIdx.x;
  const int b   = blockIdx.z;
  const int h0  = (blockIdx.x >> 3) * 16;
  const int w0  = (blockIdx.x & 7) * 16;

  for (int e = tid; e < 1024; e += 384) {
    int r = e >> 5, c = e & 31;
    int gh = h0 - 8 + r, gw = w0 - 8 + c;
    float v[8];
#pragma unroll
    for (int ci = 0; ci < 8; ++ci) v[ci] = 0.0f;
    if (gh >= 0 && gh < 128 && gw >= 0 && gw < 128) {
      const float* s = part + ((size_t)b * HW + gh * 128 + gw) * 8;
#pragma unroll
      for (int z = 0; z < 4; ++z) {
        f4v a  = *(const f4v*)(s + (size_t)z * 1048576);
        f4v b2 = *(const f4v*)(s + (size_t)z * 1048576 + 4);
        v[0] += a[0]; v[1] += a[1]; v[2] += a[2]; v[3] += a[3];
        v[4] += b2[0]; v[5] += b2[1]; v[6] += b2[2]; v[7] += b2[3];
      }
    }
#pragma unroll
    for (int ci = 0; ci < 8; ++ci) sX[ci][r * 33 + c] = v[ci];
  }
  for (int e = tid; e < 2592; e += 384) {
    int co = e & 3;
    int rest = e >> 2;
    int tap = rest % 81, ci = rest / 81;
    sW1[(ci * 81 + tap) * 4 + co] = w11[(size_t)(ci * 4 + co) * 81 + (80 - tap)];
  }
  for (int e = tid; e < 324; e += 384) {
    int tap = e % 81, ci = e / 81;
    sW0[ci * 81 + tap] = w10[(size_t)ci * 81 + (80 - tap)];
  }
  __syncthreads();

  for (int e = tid; e < 288; e += 384) {
    int r = e / 12, c2 = (e - r * 12) * 2;
    int gh = h0 - 4 + r;
    int gw0 = w0 - 4 + c2;
    float a0[4] = {0, 0, 0, 0}, a1[4] = {0, 0, 0, 0};
    for (int ci = 0; ci < 8; ++ci) {
      for (int kh = 0; kh < 9; ++kh) {
        const float* xb = &sX[ci][(r + kh) * 33 + c2];
#pragma unroll
        for (int kw = 0; kw < 9; ++kw) {
          float x0 = xb[kw], x1 = xb[kw + 1];
          const float* wp = &sW1[(ci * 81 + kh * 9 + kw) * 4];
#pragma unroll
          for (int co = 0; co < 4; ++co) {
            a0[co] += x0 * wp[co];
            a1[co] += x1 * wp[co];
          }
        }
      }
    }
    bool in0 = (gh >= 0 && gh < 128 && gw0 >= 0 && gw0 < 128);
    bool in1 = (gh >= 0 && gh < 128 && (gw0 + 1) >= 0 && (gw0 + 1) < 128);
#pragma unroll
    for (int co = 0; co < 4; ++co) {
      sT4[co][r * 25 + c2]     = in0 ? a0[co] : 0.0f;
      sT4[co][r * 25 + c2 + 1] = in1 ? a1[co] : 0.0f;
    }
  }
  __syncthreads();

  if (tid < 256) {
    int r = tid >> 4, c = tid & 15;
    float acc = 0.0f;
    for (int ci = 0; ci < 4; ++ci) {
      for (int kh = 0; kh < 9; ++kh) {
        const float* xb = &sT4[ci][(r + kh) * 25 + c];
        const float* wp = &sW0[ci * 81 + kh * 9];
#pragma unroll
        for (int kw = 0; kw < 9; ++kw) acc += xb[kw] * wp[kw];
      }
    }
    size_t o = (size_t)b * HW + (h0 + r) * 128 + (w0 + c);
    float l = lam[b];
    float vi = vin[o];
    float res = (vi + l * acc) / (1.0f + l);
    vout[o] = res;
    sRed[tid] = vi * res;
  }
  __syncthreads();
  for (int st = 128; st > 0; st >>= 1) {
    if (tid < st) sRed[tid] += sRed[tid + st];
    __syncthreads();
  }
  if (tid == 0) atomicAdd(&den[b], sRed[0]);
}

// ---------------------------------------------------------------------------
// helpers
// ---------------------------------------------------------------------------
__global__ void k_scalars(const float* __restrict__ sigma, const float* __restrict__ c_lam,
                          const float* __restrict__ c_scal, float* __restrict__ lam,
                          float* __restrict__ scal) {
  int tid = threadIdx.x;
  if (tid < BATCH) lam[tid] = spline_eval(sigma[tid], c_lam, 53, -1.0f, 51.0f);
  for (int j = tid; j < BATCH * 128; j += 256) {
    int b = j >> 7, chn = j & 127;
    float s = sigma[b];
    scal[j] = expf(spline_eval(s, c_scal + chn * 14, 14, -1.0f, 51.0f)) / (s + 1e-5f);
  }
}

// r16: also zeroes the 256-float CG scalar-slot region (rnbuf+denbuf)
__global__ void k_binit(const float* __restrict__ y, const float* __restrict__ lam,
                        float* __restrict__ bimg, float* __restrict__ x,
                        float* __restrict__ cgscal) {
  int i = blockIdx.x * 256 + threadIdx.x;
  int b = i >> 14;
  bimg[i] = y[i] / (1.0f + lam[b]);
  x[i] = 0.0f;
  if (blockIdx.x == 0) cgscal[threadIdx.x] = 0.0f;
}

// mask for c_k = 0 (bit-exact, r11-verified)
__global__ void k_fillmask(const float* __restrict__ c_sp3, u16* __restrict__ mask_c) {
  u16 hv = f2bf(fminf(fmaxf(c_sp3[0], 0.01f), 1.0f));
  u16 tmp[8];
#pragma unroll
  for (int j = 0; j < 8; ++j) tmp[j] = hv;
  size_t i = ((size_t)blockIdx.x * 256 + threadIdx.x) * 8;
  *(f4v*)(mask_c + i) = *(const f4v*)tmp;
}

// ---------------------------------------------------------------------------
// r16 parallel CG kernels. Per-iteration rn/den slots (pre-zeroed) remove all
// scalar-rotation races; grid (32,8) = 256 blocks. r19: k_cg2b removed —
// the p-update is fused into the next BtB's fused_fwd staging.
// ---------------------------------------------------------------------------
// r = p = bimg [- Bp]; atomicAdd <r,r> into rnout[b].
__global__ __launch_bounds__(256) void k_cg0p(
    const float* __restrict__ bimg, const float* __restrict__ Bp,
    float* __restrict__ r, float* __restrict__ p, float* __restrict__ rnout) {
  __shared__ float s[256];
  int b = blockIdx.y;
  size_t base = ((size_t)b << 14) + (size_t)blockIdx.x * 512;
  float local = 0.0f;
  for (int i = threadIdx.x; i < 512; i += 256) {
    float v = bimg[base + i];
    if (Bp) v -= Bp[base + i];
    r[base + i] = v;
    p[base + i] = v;
    local += v * v;
  }
  s[threadIdx.x] = local;
  __syncthreads();
  for (int st = 128; st > 0; st >>= 1) {
    if (threadIdx.x < st) s[threadIdx.x] += s[threadIdx.x + st];
    __syncthreads();
  }
  if (threadIdx.x == 0) atomicAdd(&rnout[b], s[0]);
}

// alpha = rnp/deng (guarded); x += alpha p (opt xout); r -= alpha Bp;
// atomicAdd <r',r'> into rnn[b].
__global__ __launch_bounds__(256) void k_cg2a(
    float* __restrict__ x, float* __restrict__ r, const float* __restrict__ p,
    const float* __restrict__ Bp, const float* __restrict__ rnp,
    const float* __restrict__ deng, float* __restrict__ rnn,
    float* __restrict__ xout) {
  __shared__ float s[256];
  int b = blockIdx.y;
  size_t base = ((size_t)b << 14) + (size_t)blockIdx.x * 512;
  float rnb = rnp[b];
  bool act = rnb > 1e-6f;
  float alpha = act ? rnb / deng[b] : 0.0f;
  float local = 0.0f;
  for (int i = threadIdx.x; i < 512; i += 256) {
    float pv = p[base + i];
    float xv = x[base + i] + alpha * pv;
    x[base + i] = xv;
    if (xout) xout[base + i] = xv;
    float rr = r[base + i] - alpha * Bp[base + i];
    r[base + i] = rr;
    local += rr * rr;
  }
  s[threadIdx.x] = local;
  __syncthreads();
  for (int st = 128; st > 0; st >>= 1) {
    if (threadIdx.x < st) s[threadIdx.x] += s[threadIdx.x + st];
    __syncthreads();
  }
  if (threadIdx.x == 0) atomicAdd(&rnn[b], s[0]);
}

// ---------------------------------------------------------------------------
extern "C" void kernel_launch(void* const* d_in, const int* in_sizes, int n_in_,
                              void* d_out, int out_size, void* d_ws, size_t ws_size,
                              hipStream_t stream) {
  const float* y      = (const float*)d_in[0];
  const float* sigma  = (const float*)d_in[1];
  const float* w1_0   = (const float*)d_in[2];
  const float* w1_1   = (const float*)d_in[3];
  const float* w1_2   = (const float*)d_in[4];
  const float* m1_0   = (const float*)d_in[5];
  const float* m1_1   = (const float*)d_in[6];
  const float* m1_2   = (const float*)d_in[7];
  const float* m2_w   = (const float*)d_in[8];
  const float* m3_w   = (const float*)d_in[9];
  const float* c_sp1  = (const float*)d_in[10];
  const float* c_sp2  = (const float*)d_in[11];
  const float* c_sp3  = (const float*)d_in[12];
  const float* c_lam  = (const float*)d_in[13];
  const float* c_scal = (const float*)d_in[14];
  // n_out = 2, n_in = 6 fixed by setup_inputs

  char* cur = (char*)d_ws;
  auto alloc = [&](size_t bytes) {
    char* p = cur;
    cur += (bytes + 255) & ~(size_t)255;
    return p;
  };

  // weight fragments (~3 MB)
  u16* wA_hi  = (u16*)alloc(86016 * 2);
  u16* wA_lo  = (u16*)alloc(86016 * 2);
  u16* wAm_hi = (u16*)alloc(86016 * 2);
  u16* wAm_lo = (u16*)alloc(86016 * 2);
  u16* wB_hi  = (u16*)alloc(172032 * 2);
  u16* wB_lo  = (u16*)alloc(172032 * 2);
  u16* wC2_hi = (u16*)alloc(196608 * 2);
  u16* wC2_lo = (u16*)alloc(196608 * 2);
  u16* wC3_hi = (u16*)alloc(196608 * 2);
  u16* wC3_lo = (u16*)alloc(196608 * 2);

  // region1 (67.1 MB): mask phase = P1 hi/lo bf16 planes; CG = big2c bf16
  char* region1 = alloc((size_t)16777216 * 4);
  u16* P1h   = (u16*)region1;
  u16* P1l   = (u16*)(region1 + (size_t)16777216 * 2);
  u16* big2c = (u16*)region1;
  // mask_c bf16 slice-major (33.5 MB)
  u16* mask_c = (u16*)alloc((size_t)16777216 * 2);
  // region2 (33.6 MB): mask = P2 hi/lo planes x4 batches; CG = part fp32
  char* region2 = alloc((size_t)4 * 128 * 128 * 128 * 4);
  u16*   P2h  = (u16*)region2;
  u16*   P2l  = (u16*)(region2 + (size_t)8388608 * 2);
  float* part = (float*)region2;                          // 4 x 1048576 fp32
  // region3 (4.2 MB): mask = t8 hi/lo planes; CG = t8c bf16 slice-major
  char* region3 = alloc((size_t)1048576 * 4);
  u16* t8h = (u16*)region3;
  u16* t8l = (u16*)(region3 + (size_t)1048576 * 2);
  u16* t8c = (u16*)region3;

  float* bimg  = (float*)alloc(131072 * 4);
  float* xbuf  = (float*)alloc(131072 * 4);
  float* rbuf  = (float*)alloc(131072 * 4);
  float* pbuf  = (float*)alloc(131072 * 4);
  float* pbuf2 = (float*)alloc(131072 * 4);   // r19: p ping-pong partner
  float* Bp    = (float*)alloc(131072 * 4);
  float* lam   = (float*)alloc(8 * 4);
  float* scal  = (float*)alloc(1024 * 4);
  // r16: CG scalar slots — rnbuf[16][8] then denbuf[16][8], zeroed in k_binit
  float* cgscal = (float*)alloc(256 * 4);
  float* rnbuf  = cgscal;
  float* denbuf = cgscal + 128;
  // total ~145 MB

  const dim3 blk(256);
  const dim3 blk384(384);
  const dim3 cgrid(32, 8);

  k_prepw<9, 8, 128, 8, 1, 81, 21, false><<<dim3(42), blk, 0, stream>>>(w1_2, wA_hi, wA_lo);
  k_prepw<9, 8, 128, 8, 1, 81, 21, false><<<dim3(42), blk, 0, stream>>>(m1_2, wAm_hi, wAm_lo);
  k_prepw<9, 8, 8, 1, 16, 81, 21, true><<<dim3(84), blk, 0, stream>>>(w1_2, wB_hi, wB_lo);
  k_prepw<3, 128, 128, 8, 16, 9, 3, false><<<dim3(96), blk, 0, stream>>>(m2_w, wC2_hi, wC2_lo);
  k_prepw<3, 128, 128, 8, 16, 9, 3, false><<<dim3(96), blk, 0, stream>>>(m3_w, wC3_hi, wC3_lo);

  k_scalars<<<dim3(1), blk, 0, stream>>>(sigma, c_lam, c_scal, lam, scal);
  k_binit<<<dim3(512), blk, 0, stream>>>(y, lam, bimg, xbuf, cgscal);

  // BtB: fused_fwd optionally computes p_new = r + beta*p_old during staging
  // (rnp != nullptr), writing interior pixels to pnew; downstream kernels
  // then consume pnew. vin is used only in plain mode.
  auto BtB = [&](const float* vin, float* vout, float* denp,
                 const float* rnp, const float* rnn,
                 const float* pold, float* pnew) {
    fused_fwd<1><<<dim3(64, 1, 8), blk, 0, stream>>>(
        vin, w1_0, w1_1, nullptr, t8c, nullptr, rbuf, pold, pnew, rnp, rnn);
    bconv<9, 1, 81, 21, 2, 8, 1, 3><<<dim3(64, 8, 4), blk, 0, stream>>>(
        t8c, wA_hi, nullptr, big2c, mask_c);
    bconv<9, 16, 81, 21, 1, 1, 4, 5><<<dim3(64, 8, 4), blk, 0, stream>>>(
        big2c, wB_hi, part, nullptr, nullptr);
    const float* tailvin = rnp ? (const float*)pnew : vin;
    fused_tail<<<dim3(64, 1, 8), blk384, 0, stream>>>(
        part, w1_1, w1_0, tailvin, lam, vout, denp);
  };

  // ================= outer 0: c_k = 0 (algebraic, r11-verified) =============
  // rn slots 0..6, den slots 0..5
  k_fillmask<<<dim3(8192), blk, 0, stream>>>(c_sp3, mask_c);
  k_cg0p<<<cgrid, blk, 0, stream>>>(bimg, nullptr, rbuf, pbuf, rnbuf + 0 * 8);
  {
    float* pc = pbuf;   // current p
    float* pa = pbuf2;  // alternate
    for (int it = 0; it < 6; ++it) {
      if (it == 0) {
        BtB(pc, Bp, denbuf + it * 8, nullptr, nullptr, nullptr, nullptr);
      } else {
        BtB(nullptr, Bp, denbuf + it * 8,
            rnbuf + (it - 1) * 8, rnbuf + it * 8, pc, pa);
        float* t = pc; pc = pa; pa = t;
      }
      k_cg2a<<<cgrid, blk, 0, stream>>>(xbuf, rbuf, pc, Bp,
          rnbuf + it * 8, denbuf + it * 8, rnbuf + (it + 1) * 8, nullptr);
    }
  }

  // ================= outer 1 =================
  // mask phase: hi/lo pre-split planes; mconv KS=3 at NT=4/z=2 (r19 champion)
  fused_fwd<2><<<dim3(64, 1, 8), blk, 0, stream>>>(
      xbuf, m1_0, m1_1, nullptr, t8h, t8l, nullptr, nullptr, nullptr, nullptr, nullptr);
  mconv<9, 8, 1, 81, 21, 16, 4, 4, 8, 4><<<dim3(64, 8, 2), blk, 0, stream>>>(
      t8h, t8l, wAm_hi, wAm_lo, P1h, P1l, nullptr, c_sp1, nullptr, 0, 0);
  for (int bc = 0; bc < 2; ++bc) {
    mconv<3, 128, 16, 9, 3, 16, 4, 4, 8, 4><<<dim3(64, 4, 2), blk, 0, stream>>>(
        P1h, P1l, wC2_hi, wC2_lo, P2h, P2l, nullptr, c_sp2, nullptr, bc * 4, 0);
    mconv<3, 128, 16, 9, 3, 16, 4, 4, 8, 2><<<dim3(64, 4, 2), blk, 0, stream>>>(
        P2h, P2l, wC3_hi, wC3_lo, nullptr, nullptr, mask_c, c_sp3, scal, 0, bc * 4);
  }

  // rn slots 7..13, den slots 6 (scratch) + 7..12
  BtB(xbuf, Bp, denbuf + 6 * 8, nullptr, nullptr, nullptr, nullptr);
  k_cg0p<<<cgrid, blk, 0, stream>>>(bimg, Bp, rbuf, pbuf, rnbuf + 7 * 8);
  {
    float* pc = pbuf;
    float* pa = pbuf2;
    for (int it = 0; it < 6; ++it) {
      if (it == 0) {
        BtB(pc, Bp, denbuf + (7 + it) * 8, nullptr, nullptr, nullptr, nullptr);
      } else {
        BtB(nullptr, Bp, denbuf + (7 + it) * 8,
            rnbuf + (7 + it - 1) * 8, rnbuf + (7 + it) * 8, pc, pa);
        float* t = pc; pc = pa; pa = t;
      }
      float* xout = (it == 5) ? (float*)d_out : nullptr;
      k_cg2a<<<cgrid, blk, 0, stream>>>(xbuf, rbuf, pc, Bp,
          rnbuf + (7 + it) * 8, denbuf + (7 + it) * 8, rnbuf + (8 + it) * 8, xout);
    }
  }
}

// Round 13
// 2677.354 us; speedup vs baseline: 1.4869x; 1.0693x over previous
//
#include <hip/hip_runtime.h>

#define HW 16384
#define BATCH 8

typedef unsigned short u16;
typedef __attribute__((ext_vector_type(8))) short bfrag;   // 8 bf16 in 4 VGPRs
typedef __attribute__((ext_vector_type(4))) float ffrag;   // MFMA accumulator
typedef __attribute__((ext_vector_type(4))) float f4v;

// ---------------------------------------------------------------------------
__device__ __forceinline__ u16 f2bf(float f) {
  unsigned int u = __float_as_uint(f);
  u += 0x7FFFu + ((u >> 16) & 1u);
  return (u16)(u >> 16);
}
__device__ __forceinline__ float bf2f(u16 h) {
  return __uint_as_float(((unsigned int)h) << 16);
}
__device__ __forceinline__ ffrag mfma16(bfrag a, bfrag b, ffrag c) {
  return __builtin_amdgcn_mfma_f32_16x16x32_bf16(a, b, c, 0, 0, 0);
}

__device__ __forceinline__ float spline_eval(float x, const float* __restrict__ c,
                                             int K, float xmin, float xmax) {
  float step = (xmax - xmin) / (float)(K - 1);
  float t = (x - xmin) / step;
  float fidx = floorf(t);
  fidx = fminf(fmaxf(fidx, 0.0f), (float)(K - 2));
  int idx = (int)fidx;
  float frac = t - fidx;
  return c[idx] * (1.0f - frac) + c[idx + 1] * frac;
}
__device__ __forceinline__ float spline31(float x, const float* __restrict__ c) {
  float t = x * 10.0f;
  float fi = floorf(t);
  fi = fminf(fmaxf(fi, 0.0f), 29.0f);
  int i = (int)fi;
  float fr = t - fi;
  return c[i] * (1.0f - fr) + c[i + 1] * fr;
}

// ---------------------------------------------------------------------------
// Weight prep: OIHW fp32 -> MFMA B-fragment order, bf16 hi/lo planes. (r4-r11)
// ---------------------------------------------------------------------------
template<int KS, int CIW, int CO, int NTT, int NSLICE, int TAPS, int CHUNKS, bool TR>
__global__ void k_prepw(const float* __restrict__ W, u16* __restrict__ hi,
                        u16* __restrict__ lo) {
  int gid = blockIdx.x * 256 + threadIdx.x;
  const int total = NSLICE * CHUNKS * NTT * 64;
  if (gid >= total) return;
  int L = gid & 63;
  int rest = gid >> 6;
  int ntg = rest % NTT; rest /= NTT;
  int ch = rest % CHUNKS;
  int sl = rest / CHUNKS;
  int q = L >> 4, n = L & 15;
  int tap = ch * 4 + q;
  int co = ntg * 16 + n;
  int dh = tap / KS, dw = tap - dh * KS;
  for (int j = 0; j < 8; ++j) {
    int ci = sl * 8 + j;
    float v = 0.0f;
    if (tap < TAPS && co < CO) {
      if (TR)
        v = W[(((size_t)ci * CO + co) * KS + (KS - 1 - dh)) * KS + (KS - 1 - dw)];
      else
        v = W[(((size_t)co * CIW + ci) * KS + dh) * KS + dw];
    }
    u16 h = f2bf(v);
    hi[(size_t)gid * 8 + j] = h;
    lo[(size_t)gid * 8 + j] = f2bf(v - bf2f(h));
  }
}

// ---------------------------------------------------------------------------
// bconv (r6-verified core + KSPLIT; plain staging — dbuf regressed in r14):
// LDS-staged 1-term bf16 MFMA conv.
// KSPLIT>1: blockIdx.z = K-slice group (co-group fixed 0), partial fp32 out.
// EPI 3: v*m^2, m from mask_c buffer -> slice-major bf16 (128ch)
// EPI 6: v*m^2, m = scalar msc[0] (outer-0 constant mask; bit-identical to
//        EPI3 since msc holds bf2f(f2bf(clip)) — skips the 33.5 MB read)
// EPI 5: partial fp32, co<8 -> part[(bz*BATCH+bb)*HW + px]*8 + co
// ---------------------------------------------------------------------------
template<int KS, int SLICES, int TAPS, int CHUNKS, int NT, int NTT, int KSPLIT, int EPI>
__global__ __launch_bounds__(256) void bconv(
    const u16* __restrict__ in, const u16* __restrict__ wHi,
    float* __restrict__ outF, u16* __restrict__ outBf,
    const u16* __restrict__ mskc, const float* __restrict__ msc)
{
  constexpr int P   = KS / 2;
  constexpr int IW  = 16 + 2 * P;
  constexpr int IH  = 16 + 2 * P;
  constexpr int SPB = SLICES / KSPLIT;

  __shared__ __align__(16) u16 sA[IH * IW * 8];

  const int tid = threadIdx.x;
  const int wv  = tid >> 6;
  const int L   = tid & 63;
  const int q   = L >> 4;
  const int n16 = L & 15;

  const int tx = blockIdx.x & 7, ty = blockIdx.x >> 3;
  const int w0 = tx * 16, h0 = ty * 16;
  const int bb = blockIdx.y;
  const int bz = blockIdx.z;
  const int slc0 = (KSPLIT > 1) ? bz * SPB : 0;
  const int cog  = (KSPLIT > 1) ? 0 : bz;

  ffrag acc[4][NT];
#pragma unroll
  for (int i = 0; i < 4; ++i)
#pragma unroll
    for (int t = 0; t < NT; ++t) acc[i][t] = (ffrag)0.0f;

  for (int s = 0; s < SPB; ++s) {
    const int slc = slc0 + s;
    __syncthreads();
    for (int e = tid; e < IH * IW; e += 256) {
      int ih = e / IW, iw = e - ih * IW;
      int gh = h0 + ih - P, gw = w0 + iw - P;
      f4v v = (f4v)0.0f;
      if (gh >= 0 && gh < 128 && gw >= 0 && gw < 128)
        v = *(const f4v*)(in + (((size_t)(bb * SLICES + slc) * HW) + gh * 128 + gw) * 8);
      *(f4v*)(sA + (size_t)e * 8) = v;
    }
    __syncthreads();

    const u16* wS = wHi + (size_t)slc * CHUNKS * NTT * 512;
    for (int ch = 0; ch < CHUNKS; ++ch) {
      int tap = ch * 4 + q;
      int dh = 0, dw = 0;
      if (tap < TAPS) { dh = tap / KS; dw = tap - dh * KS; }
      int toff = dh * IW + dw;
      bfrag A[4];
#pragma unroll
      for (int i = 0; i < 4; ++i)
        A[i] = *(const bfrag*)(sA + ((wv * 4 + i) * IW + n16 + toff) * 8);
#pragma unroll
      for (int t = 0; t < NT; ++t) {
        bfrag B = *(const bfrag*)(wS + ((size_t)ch * NTT + cog * NT + t) * 512 + L * 8);
#pragma unroll
        for (int i = 0; i < 4; ++i) acc[i][t] = mfma16(A[i], B, acc[i][t]);
      }
    }
  }

  float mconst = 0.0f;
  if (EPI == 6) mconst = msc[0];

#pragma unroll
  for (int i = 0; i < 4; ++i) {
    const int h = h0 + wv * 4 + i;
#pragma unroll
    for (int t = 0; t < NT; ++t) {
      const int co = cog * (NT * 16) + t * 16 + n16;
#pragma unroll
      for (int r = 0; r < 4; ++r) {
        const int w = w0 + q * 4 + r;
        float v = acc[i][t][r];
        if (EPI == 3) {
          size_t o = (((size_t)(bb * 16 + (co >> 3)) * HW) + h * 128 + w) * 8 + (co & 7);
          float m = bf2f(mskc[o]);
          outBf[o] = f2bf(v * m * m);
        } else if (EPI == 6) {
          size_t o = (((size_t)(bb * 16 + (co >> 3)) * HW) + h * 128 + w) * 8 + (co & 7);
          outBf[o] = f2bf(v * mconst * mconst);
        } else if (EPI == 5) {
          if (n16 < 8)
            outF[(((size_t)bz * BATCH + bb) * HW + h * 128 + w) * 8 + n16] = v;
        }
      }
    }
  }
}

// ---------------------------------------------------------------------------
// mconv (r19 champion: TH=16, NT=4, z=2, pre-split bf16 hi/lo input, dbuf
// staging — 70 us, MfmaUtil 43%, FETCH 39 MB. r20's NT=2/z=4 regressed: 77us,
// FETCH 85 MB — z-groups duplicate the 16-slice staging halo).
// EPI 4: spline31(|v|) -> hi/lo bf16 slice-major planes
// EPI 2: clip spline -> mask_c bf16
// ---------------------------------------------------------------------------
template<int KS, int CIN, int NSLICE, int TAPS, int CHUNKS,
         int TH, int MTW, int NT, int NTT, int EPI>
__global__ __launch_bounds__(256) void mconv(
    const u16* __restrict__ inH, const u16* __restrict__ inL,
    const u16* __restrict__ wHi, const u16* __restrict__ wLo,
    u16* __restrict__ outH, u16* __restrict__ outL,
    u16* __restrict__ outBf,
    const float* __restrict__ sp, const float* __restrict__ sl,
    int binOfs, int boutOfs)
{
  constexpr int P  = KS / 2;
  constexpr int IW = 16 + 2 * P;
  constexpr int IH = TH + 2 * P;
  constexpr int NE = (IH * IW + 255) / 256;

  __shared__ __align__(16) u16 sHi[IH * IW * 8];
  __shared__ __align__(16) u16 sLo[IH * IW * 8];

  const int tid = threadIdx.x;
  const int wv  = tid >> 6;
  const int L   = tid & 63;
  const int q   = L >> 4;
  const int n16 = L & 15;

  const int tx = blockIdx.x & 7;
  const int ty = blockIdx.x >> 3;
  const int w0 = tx * 16, h0 = ty * TH;
  const int bin  = (int)blockIdx.y + binOfs;
  const int bout = (int)blockIdx.y + boutOfs;
  const int bz = blockIdx.z;

  ffrag acc[MTW][NT];
#pragma unroll
  for (int i = 0; i < MTW; ++i)
#pragma unroll
    for (int t = 0; t < NT; ++t) acc[i][t] = (ffrag)0.0f;

  auto ldslice = [&](int slc, f4v* ph, f4v* pl) {
#pragma unroll
    for (int k = 0; k < NE; ++k) {
      int e = tid + k * 256;
      ph[k] = (f4v)0.0f;
      pl[k] = (f4v)0.0f;
      if (e < IH * IW) {
        int ih = e / IW, iw = e - ih * IW;
        int gh = h0 + ih - P, gw = w0 + iw - P;
        if (gh >= 0 && gh < 128 && gw >= 0 && gw < 128) {
          size_t o = (((size_t)(bin * NSLICE + slc) * HW) + gh * 128 + gw) * 8;
          ph[k] = *(const f4v*)(inH + o);
          pl[k] = *(const f4v*)(inL + o);
        }
      }
    }
  };

  f4v rh[NE], rl[NE];
  ldslice(0, rh, rl);

  for (int slc = 0; slc < NSLICE; ++slc) {
    __syncthreads();
#pragma unroll
    for (int k = 0; k < NE; ++k) {
      int e = tid + k * 256;
      if (e < IH * IW) {
        *(f4v*)(sHi + (size_t)e * 8) = rh[k];
        *(f4v*)(sLo + (size_t)e * 8) = rl[k];
      }
    }
    f4v nh[NE], nl[NE];
    if (slc + 1 < NSLICE) {
      ldslice(slc + 1, nh, nl);
    } else {
#pragma unroll
      for (int k = 0; k < NE; ++k) { nh[k] = (f4v)0.0f; nl[k] = (f4v)0.0f; }
    }
    __syncthreads();

    const u16* wHs = wHi + (size_t)slc * CHUNKS * NTT * 512;
    const u16* wLs = wLo + (size_t)slc * CHUNKS * NTT * 512;
    for (int ch = 0; ch < CHUNKS; ++ch) {
      int tap = ch * 4 + q;
      int dh = tap / KS;
      int dw = tap - dh * KS;
      int toff = (tap < TAPS) ? (dh * IW + dw) : 0;
      bfrag Ah[MTW], Al[MTW];
#pragma unroll
      for (int i = 0; i < MTW; ++i) {
        int a8 = ((wv * MTW + i) * IW + n16 + toff) * 8;
        Ah[i] = *(const bfrag*)(sHi + a8);
        Al[i] = *(const bfrag*)(sLo + a8);
      }
#pragma unroll
      for (int t = 0; t < NT; ++t) {
        size_t off = ((size_t)ch * NTT + bz * NT + t) * 512 + L * 8;
        bfrag Bh = *(const bfrag*)(wHs + off);
        bfrag Bl = *(const bfrag*)(wLs + off);
#pragma unroll
        for (int i = 0; i < MTW; ++i) {
          acc[i][t] = mfma16(Ah[i], Bh, acc[i][t]);
          acc[i][t] = mfma16(Ah[i], Bl, acc[i][t]);
          acc[i][t] = mfma16(Al[i], Bh, acc[i][t]);
        }
      }
    }
#pragma unroll
    for (int k = 0; k < NE; ++k) { rh[k] = nh[k]; rl[k] = nl[k]; }
  }

#pragma unroll
  for (int i = 0; i < MTW; ++i) {
    const int h = h0 + wv * MTW + i;
#pragma unroll
    for (int t = 0; t < NT; ++t) {
      const int co = bz * (NT * 16) + t * 16 + n16;
#pragma unroll
      for (int r = 0; r < 4; ++r) {
        const int w = w0 + q * 4 + r;
        float v = acc[i][t][r];
        if (EPI == 4) {
          float x = spline31(fabsf(v), sp);
          u16 hb = f2bf(x);
          size_t o = (((size_t)(bout * 16 + (co >> 3)) * HW) + h * 128 + w) * 8 + (co & 7);
          outH[o] = hb;
          outL[o] = f2bf(x - bf2f(hb));
        } else if (EPI == 2) {
          float s = sl[bout * 128 + co];
          float x = spline31(s * fabsf(v), sp);
          x = fminf(fmaxf(x, 0.01f), 1.0f);
          size_t o = (((size_t)(bout * 16 + (co >> 3)) * HW) + h * 128 + w) * 8 + (co & 7);
          outBf[o] = f2bf(x);
        }
      }
    }
  }
}

// ---------------------------------------------------------------------------
// fused forward 1->4->8 (r19 form — VGPR 176 @ 8 waves/CU is this kernel's
// operating point; r17 bounds-hint and r20 loop-split both caused massive
// scratch spill. DO NOT touch register pressure here.)
// r19: CG p-update fused into staging (rnp != nullptr).
// OUT 0: fp32 NHWC8 | OUT 1: bf16 8ch | OUT 2: bf16 hi/lo 8ch planes
// ---------------------------------------------------------------------------
template<int OUT>
__global__ __launch_bounds__(256) void fused_fwd(
    const float* __restrict__ in, const float* __restrict__ wA,
    const float* __restrict__ wB, float* __restrict__ outF,
    u16* __restrict__ outBf, u16* __restrict__ outLo,
    const float* __restrict__ rr, const float* __restrict__ pold,
    float* __restrict__ pnew, const float* __restrict__ rnp,
    const float* __restrict__ rnn)
{
  __shared__ float sX[32 * 32];
  __shared__ float sT4[4][24 * 25];
  __shared__ float sWA[81 * 4];
  __shared__ float sWB[4 * 81 * 8];

  const int tid = threadIdx.x;
  const int b   = blockIdx.z;
  const int h0  = (blockIdx.x >> 3) * 16;
  const int w0  = (blockIdx.x & 7) * 16;

  const bool doP = (rnp != nullptr);
  float beta = 0.0f;
  if (doP) {
    float rnb = rnp[b];
    beta = (rnb > 1e-6f) ? (rnn[b] / rnb) : 0.0f;
  }

  for (int e = tid; e < 1024; e += 256) {
    int r = e >> 5, c = e & 31;
    int gh = h0 - 8 + r, gw = w0 - 8 + c;
    float v = 0.0f;
    if (gh >= 0 && gh < 128 && gw >= 0 && gw < 128) {
      size_t idx = (size_t)b * HW + gh * 128 + gw;
      if (doP) {
        v = rr[idx] + beta * pold[idx];
        if (r >= 8 && r < 24 && c >= 8 && c < 24) pnew[idx] = v;
      } else {
        v = in[idx];
      }
    }
    sX[e] = v;
  }
  for (int e = tid; e < 324; e += 256) {
    int co = e & 3, tap = e >> 2;
    sWA[tap * 4 + co] = wA[co * 81 + tap];
  }
  for (int e = tid; e < 2592; e += 256) {
    int co = e & 7;
    int rest = e >> 3;
    int tap = rest % 81, ci = rest / 81;
    sWB[(ci * 81 + tap) * 8 + co] = wB[((size_t)co * 4 + ci) * 81 + tap];
  }
  __syncthreads();

  for (int e = tid; e < 576; e += 256) {
    int r = e / 24, c = e - (e / 24) * 24;
    int gh = h0 - 4 + r, gw = w0 - 4 + c;
    float a0 = 0.0f, a1 = 0.0f, a2 = 0.0f, a3 = 0.0f;
    if (gh >= 0 && gh < 128 && gw >= 0 && gw < 128) {
      for (int kh = 0; kh < 9; ++kh) {
#pragma unroll
        for (int kw = 0; kw < 9; ++kw) {
          float x = sX[(r + kh) * 32 + (c + kw)];
          const float* wp = &sWA[(kh * 9 + kw) * 4];
          a0 += x * wp[0]; a1 += x * wp[1]; a2 += x * wp[2]; a3 += x * wp[3];
        }
      }
    }
    sT4[0][r * 25 + c] = a0;
    sT4[1][r * 25 + c] = a1;
    sT4[2][r * 25 + c] = a2;
    sT4[3][r * 25 + c] = a3;
  }
  __syncthreads();

  const int c  = tid & 15;
  const int r0 = tid >> 4;
  float acc[8];
#pragma unroll
  for (int co = 0; co < 8; ++co) acc[co] = 0.0f;

  for (int ci = 0; ci < 4; ++ci) {
    const float* t4c = sT4[ci];
    for (int kh = 0; kh < 9; ++kh) {
#pragma unroll
      for (int kw = 0; kw < 9; ++kw) {
        float x0 = t4c[(r0 + kh) * 25 + c + kw];
        const float* wp = &sWB[(ci * 81 + kh * 9 + kw) * 8];
#pragma unroll
        for (int co = 0; co < 8; ++co) acc[co] += x0 * wp[co];
      }
    }
  }

  {
    const int h = h0 + r0;
    const int w = w0 + c;
#pragma unroll
    for (int co = 0; co < 8; ++co) {
      float v = acc[co];
      if (OUT == 0) {
        outF[(((size_t)b * 128 + h) * 128 + w) * 8 + co] = v;
      } else if (OUT == 1) {
        outBf[((size_t)b * HW + h * 128 + w) * 8 + co] = f2bf(v);
      } else {
        u16 hb = f2bf(v);
        size_t o = ((size_t)b * HW + h * 128 + w) * 8 + co;
        outBf[o] = hb;
        outLo[o] = f2bf(v - bf2f(hb));
      }
    }
  }
}

// ---------------------------------------------------------------------------
// fused tail (r17: 384 threads — middle stage 288 items single-pass,
// occupancy 8 -> 12 waves/CU; kept).
// 8 ->(9x9 t-conv) 4 ->(9x9 t-conv) 1, then (vin + lam*v)/(1+lam);
// per-block <vin, vout> partial -> atomicAdd den[b]. grid (64,1,8).
// ---------------------------------------------------------------------------
__global__ __launch_bounds__(384) void fused_tail(
    const float* __restrict__ part, const float* __restrict__ w11,
    const float* __restrict__ w10, const float* __restrict__ vin,
    const float* __restrict__ lam, float* __restrict__ vout,
    float* __restrict__ den)
{
  __shared__ float sX[8][1057];
  __shared__ float sT4[4][24 * 25];
  __shared__ float sW1[8 * 81 * 4];
  __shared__ float sW0[4 * 81];
  __shared__ float sRed[256];

  const int tid = threadIdx.x;
  const int b   = blockIdx.z;
  const int h0  = (blockIdx.x >> 3) * 16;
  const int w0  = (blockIdx.x & 7) * 16;

  for (int e = tid; e < 1024; e += 384) {
    int r = e >> 5, c = e & 31;
    int gh = h0 - 8 + r, gw = w0 - 8 + c;
    float v[8];
#pragma unroll
    for (int ci = 0; ci < 8; ++ci) v[ci] = 0.0f;
    if (gh >= 0 && gh < 128 && gw >= 0 && gw < 128) {
      const float* s = part + ((size_t)b * HW + gh * 128 + gw) * 8;
#pragma unroll
      for (int z = 0; z < 4; ++z) {
        f4v a  = *(const f4v*)(s + (size_t)z * 1048576);
        f4v b2 = *(const f4v*)(s + (size_t)z * 1048576 + 4);
        v[0] += a[0]; v[1] += a[1]; v[2] += a[2]; v[3] += a[3];
        v[4] += b2[0]; v[5] += b2[1]; v[6] += b2[2]; v[7] += b2[3];
      }
    }
#pragma unroll
    for (int ci = 0; ci < 8; ++ci) sX[ci][r * 33 + c] = v[ci];
  }
  for (int e = tid; e < 2592; e += 384) {
    int co = e & 3;
    int rest = e >> 2;
    int tap = rest % 81, ci = rest / 81;
    sW1[(ci * 81 + tap) * 4 + co] = w11[(size_t)(ci * 4 + co) * 81 + (80 - tap)];
  }
  for (int e = tid; e < 324; e += 384) {
    int tap = e % 81, ci = e / 81;
    sW0[ci * 81 + tap] = w10[(size_t)ci * 81 + (80 - tap)];
  }
  __syncthreads();

  for (int e = tid; e < 288; e += 384) {
    int r = e / 12, c2 = (e - r * 12) * 2;
    int gh = h0 - 4 + r;
    int gw0 = w0 - 4 + c2;
    float a0[4] = {0, 0, 0, 0}, a1[4] = {0, 0, 0, 0};
    for (int ci = 0; ci < 8; ++ci) {
      for (int kh = 0; kh < 9; ++kh) {
        const float* xb = &sX[ci][(r + kh) * 33 + c2];
#pragma unroll
        for (int kw = 0; kw < 9; ++kw) {
          float x0 = xb[kw], x1 = xb[kw + 1];
          const float* wp = &sW1[(ci * 81 + kh * 9 + kw) * 4];
#pragma unroll
          for (int co = 0; co < 4; ++co) {
            a0[co] += x0 * wp[co];
            a1[co] += x1 * wp[co];
          }
        }
      }
    }
    bool in0 = (gh >= 0 && gh < 128 && gw0 >= 0 && gw0 < 128);
    bool in1 = (gh >= 0 && gh < 128 && (gw0 + 1) >= 0 && (gw0 + 1) < 128);
#pragma unroll
    for (int co = 0; co < 4; ++co) {
      sT4[co][r * 25 + c2]     = in0 ? a0[co] : 0.0f;
      sT4[co][r * 25 + c2 + 1] = in1 ? a1[co] : 0.0f;
    }
  }
  __syncthreads();

  if (tid < 256) {
    int r = tid >> 4, c = tid & 15;
    float acc = 0.0f;
    for (int ci = 0; ci < 4; ++ci) {
      for (int kh = 0; kh < 9; ++kh) {
        const float* xb = &sT4[ci][(r + kh) * 25 + c];
        const float* wp = &sW0[ci * 81 + kh * 9];
#pragma unroll
        for (int kw = 0; kw < 9; ++kw) acc += xb[kw] * wp[kw];
      }
    }
    size_t o = (size_t)b * HW + (h0 + r) * 128 + (w0 + c);
    float l = lam[b];
    float vi = vin[o];
    float res = (vi + l * acc) / (1.0f + l);
    vout[o] = res;
    sRed[tid] = vi * res;
  }
  __syncthreads();
  for (int st = 128; st > 0; st >>= 1) {
    if (tid < st) sRed[tid] += sRed[tid + st];
    __syncthreads();
  }
  if (tid == 0) atomicAdd(&den[b], sRed[0]);
}

// ---------------------------------------------------------------------------
// helpers
// ---------------------------------------------------------------------------
// r23: also emits msk0[0] = bf2f(f2bf(clip(c_sp3[0]))) — bitwise identical
// to the old k_fillmask->EPI3 round trip, consumed by bconv EPI6 in outer 0.
__global__ void k_scalars(const float* __restrict__ sigma, const float* __restrict__ c_lam,
                          const float* __restrict__ c_scal, const float* __restrict__ c_sp3,
                          float* __restrict__ lam, float* __restrict__ scal,
                          float* __restrict__ msk0) {
  int tid = threadIdx.x;
  if (tid < BATCH) lam[tid] = spline_eval(sigma[tid], c_lam, 53, -1.0f, 51.0f);
  if (tid == 0) msk0[0] = bf2f(f2bf(fminf(fmaxf(c_sp3[0], 0.01f), 1.0f)));
  for (int j = tid; j < BATCH * 128; j += 256) {
    int b = j >> 7, chn = j & 127;
    float s = sigma[b];
    scal[j] = expf(spline_eval(s, c_scal + chn * 14, 14, -1.0f, 51.0f)) / (s + 1e-5f);
  }
}

// r16: also zeroes the 256-float CG scalar-slot region (rnbuf+denbuf)
__global__ void k_binit(const float* __restrict__ y, const float* __restrict__ lam,
                        float* __restrict__ bimg, float* __restrict__ x,
                        float* __restrict__ cgscal) {
  int i = blockIdx.x * 256 + threadIdx.x;
  int b = i >> 14;
  bimg[i] = y[i] / (1.0f + lam[b]);
  x[i] = 0.0f;
  if (blockIdx.x == 0) cgscal[threadIdx.x] = 0.0f;
}

// ---------------------------------------------------------------------------
// r16 parallel CG kernels. Per-iteration rn/den slots (pre-zeroed) remove all
// scalar-rotation races; grid (32,8) = 256 blocks. r19: k_cg2b removed —
// the p-update is fused into the next BtB's fused_fwd staging.
// ---------------------------------------------------------------------------
// r = p = bimg [- Bp]; atomicAdd <r,r> into rnout[b].
__global__ __launch_bounds__(256) void k_cg0p(
    const float* __restrict__ bimg, const float* __restrict__ Bp,
    float* __restrict__ r, float* __restrict__ p, float* __restrict__ rnout) {
  __shared__ float s[256];
  int b = blockIdx.y;
  size_t base = ((size_t)b << 14) + (size_t)blockIdx.x * 512;
  float local = 0.0f;
  for (int i = threadIdx.x; i < 512; i += 256) {
    float v = bimg[base + i];
    if (Bp) v -= Bp[base + i];
    r[base + i] = v;
    p[base + i] = v;
    local += v * v;
  }
  s[threadIdx.x] = local;
  __syncthreads();
  for (int st = 128; st > 0; st >>= 1) {
    if (threadIdx.x < st) s[threadIdx.x] += s[threadIdx.x + st];
    __syncthreads();
  }
  if (threadIdx.x == 0) atomicAdd(&rnout[b], s[0]);
}

// alpha = rnp/deng (guarded); x += alpha p (opt xout); r -= alpha Bp;
// atomicAdd <r',r'> into rnn[b].
__global__ __launch_bounds__(256) void k_cg2a(
    float* __restrict__ x, float* __restrict__ r, const float* __restrict__ p,
    const float* __restrict__ Bp, const float* __restrict__ rnp,
    const float* __restrict__ deng, float* __restrict__ rnn,
    float* __restrict__ xout) {
  __shared__ float s[256];
  int b = blockIdx.y;
  size_t base = ((size_t)b << 14) + (size_t)blockIdx.x * 512;
  float rnb = rnp[b];
  bool act = rnb > 1e-6f;
  float alpha = act ? rnb / deng[b] : 0.0f;
  float local = 0.0f;
  for (int i = threadIdx.x; i < 512; i += 256) {
    float pv = p[base + i];
    float xv = x[base + i] + alpha * pv;
    x[base + i] = xv;
    if (xout) xout[base + i] = xv;
    float rr = r[base + i] - alpha * Bp[base + i];
    r[base + i] = rr;
    local += rr * rr;
  }
  s[threadIdx.x] = local;
  __syncthreads();
  for (int st = 128; st > 0; st >>= 1) {
    if (threadIdx.x < st) s[threadIdx.x] += s[threadIdx.x + st];
    __syncthreads();
  }
  if (threadIdx.x == 0) atomicAdd(&rnn[b], s[0]);
}

// ---------------------------------------------------------------------------
extern "C" void kernel_launch(void* const* d_in, const int* in_sizes, int n_in_,
                              void* d_out, int out_size, void* d_ws, size_t ws_size,
                              hipStream_t stream) {
  const float* y      = (const float*)d_in[0];
  const float* sigma  = (const float*)d_in[1];
  const float* w1_0   = (const float*)d_in[2];
  const float* w1_1   = (const float*)d_in[3];
  const float* w1_2   = (const float*)d_in[4];
  const float* m1_0   = (const float*)d_in[5];
  const float* m1_1   = (const float*)d_in[6];
  const float* m1_2   = (const float*)d_in[7];
  const float* m2_w   = (const float*)d_in[8];
  const float* m3_w   = (const float*)d_in[9];
  const float* c_sp1  = (const float*)d_in[10];
  const float* c_sp2  = (const float*)d_in[11];
  const float* c_sp3  = (const float*)d_in[12];
  const float* c_lam  = (const float*)d_in[13];
  const float* c_scal = (const float*)d_in[14];
  // n_out = 2, n_in = 6 fixed by setup_inputs

  char* cur = (char*)d_ws;
  auto alloc = [&](size_t bytes) {
    char* p = cur;
    cur += (bytes + 255) & ~(size_t)255;
    return p;
  };

  // weight fragments (~3 MB)
  u16* wA_hi  = (u16*)alloc(86016 * 2);
  u16* wA_lo  = (u16*)alloc(86016 * 2);
  u16* wAm_hi = (u16*)alloc(86016 * 2);
  u16* wAm_lo = (u16*)alloc(86016 * 2);
  u16* wB_hi  = (u16*)alloc(172032 * 2);
  u16* wB_lo  = (u16*)alloc(172032 * 2);
  u16* wC2_hi = (u16*)alloc(196608 * 2);
  u16* wC2_lo = (u16*)alloc(196608 * 2);
  u16* wC3_hi = (u16*)alloc(196608 * 2);
  u16* wC3_lo = (u16*)alloc(196608 * 2);

  // region1 (67.1 MB): mask phase = P1 hi/lo bf16 planes; CG = big2c bf16
  char* region1 = alloc((size_t)16777216 * 4);
  u16* P1h   = (u16*)region1;
  u16* P1l   = (u16*)(region1 + (size_t)16777216 * 2);
  u16* big2c = (u16*)region1;
  // mask_c bf16 slice-major (33.5 MB) — written by mconv EPI2, read by EPI3
  u16* mask_c = (u16*)alloc((size_t)16777216 * 2);
  // region2 (33.6 MB): mask = P2 hi/lo planes x4 batches; CG = part fp32
  char* region2 = alloc((size_t)4 * 128 * 128 * 128 * 4);
  u16*   P2h  = (u16*)region2;
  u16*   P2l  = (u16*)(region2 + (size_t)8388608 * 2);
  float* part = (float*)region2;                          // 4 x 1048576 fp32
  // region3 (4.2 MB): mask = t8 hi/lo planes; CG = t8c bf16 slice-major
  char* region3 = alloc((size_t)1048576 * 4);
  u16* t8h = (u16*)region3;
  u16* t8l = (u16*)(region3 + (size_t)1048576 * 2);
  u16* t8c = (u16*)region3;

  float* bimg  = (float*)alloc(131072 * 4);
  float* xbuf  = (float*)alloc(131072 * 4);
  float* rbuf  = (float*)alloc(131072 * 4);
  float* pbuf  = (float*)alloc(131072 * 4);
  float* pbuf2 = (float*)alloc(131072 * 4);   // r19: p ping-pong partner
  float* Bp    = (float*)alloc(131072 * 4);
  float* lam   = (float*)alloc(8 * 4);
  float* scal  = (float*)alloc(1024 * 4);
  float* msk0  = (float*)alloc(4);            // r23: outer-0 constant mask
  // r16: CG scalar slots — rnbuf[16][8] then denbuf[16][8], zeroed in k_binit
  float* cgscal = (float*)alloc(256 * 4);
  float* rnbuf  = cgscal;
  float* denbuf = cgscal + 128;
  // total ~145 MB

  const dim3 blk(256);
  const dim3 blk384(384);
  const dim3 cgrid(32, 8);

  k_prepw<9, 8, 128, 8, 1, 81, 21, false><<<dim3(42), blk, 0, stream>>>(w1_2, wA_hi, wA_lo);
  k_prepw<9, 8, 128, 8, 1, 81, 21, false><<<dim3(42), blk, 0, stream>>>(m1_2, wAm_hi, wAm_lo);
  k_prepw<9, 8, 8, 1, 16, 81, 21, true><<<dim3(84), blk, 0, stream>>>(w1_2, wB_hi, wB_lo);
  k_prepw<3, 128, 128, 8, 16, 9, 3, false><<<dim3(96), blk, 0, stream>>>(m2_w, wC2_hi, wC2_lo);
  k_prepw<3, 128, 128, 8, 16, 9, 3, false><<<dim3(96), blk, 0, stream>>>(m3_w, wC3_hi, wC3_lo);

  k_scalars<<<dim3(1), blk, 0, stream>>>(sigma, c_lam, c_scal, c_sp3, lam, scal, msk0);
  k_binit<<<dim3(512), blk, 0, stream>>>(y, lam, bimg, xbuf, cgscal);

  // BtB: fused_fwd optionally computes p_new = r + beta*p_old during staging
  // (rnp != nullptr); cm=true -> EPI6 (scalar constant mask, outer 0 — skips
  // the 33.5 MB mask_c read and the k_fillmask dispatch; bit-exact).
  auto BtB = [&](const float* vin, float* vout, float* denp,
                 const float* rnp, const float* rnn,
                 const float* pold, float* pnew, bool cm) {
    fused_fwd<1><<<dim3(64, 1, 8), blk, 0, stream>>>(
        vin, w1_0, w1_1, nullptr, t8c, nullptr, rbuf, pold, pnew, rnp, rnn);
    if (cm) {
      bconv<9, 1, 81, 21, 2, 8, 1, 6><<<dim3(64, 8, 4), blk, 0, stream>>>(
          t8c, wA_hi, nullptr, big2c, nullptr, msk0);
    } else {
      bconv<9, 1, 81, 21, 2, 8, 1, 3><<<dim3(64, 8, 4), blk, 0, stream>>>(
          t8c, wA_hi, nullptr, big2c, mask_c, nullptr);
    }
    bconv<9, 16, 81, 21, 1, 1, 4, 5><<<dim3(64, 8, 4), blk, 0, stream>>>(
        big2c, wB_hi, part, nullptr, nullptr, nullptr);
    const float* tailvin = rnp ? (const float*)pnew : vin;
    fused_tail<<<dim3(64, 1, 8), blk384, 0, stream>>>(
        part, w1_1, w1_0, tailvin, lam, vout, denp);
  };

  // ================= outer 0: c_k = 0 (constant mask -> EPI6) ===============
  // rn slots 0..6, den slots 0..5
  k_cg0p<<<cgrid, blk, 0, stream>>>(bimg, nullptr, rbuf, pbuf, rnbuf + 0 * 8);
  {
    float* pc = pbuf;   // current p
    float* pa = pbuf2;  // alternate
    for (int it = 0; it < 6; ++it) {
      if (it == 0) {
        BtB(pc, Bp, denbuf + it * 8, nullptr, nullptr, nullptr, nullptr, true);
      } else {
        BtB(nullptr, Bp, denbuf + it * 8,
            rnbuf + (it - 1) * 8, rnbuf + it * 8, pc, pa, true);
        float* t = pc; pc = pa; pa = t;
      }
      k_cg2a<<<cgrid, blk, 0, stream>>>(xbuf, rbuf, pc, Bp,
          rnbuf + it * 8, denbuf + it * 8, rnbuf + (it + 1) * 8, nullptr);
    }
  }

  // ================= outer 1 =================
  // mask phase: hi/lo pre-split planes; mconv KS=3 at NT=4/z=2 (r19 champion)
  fused_fwd<2><<<dim3(64, 1, 8), blk, 0, stream>>>(
      xbuf, m1_0, m1_1, nullptr, t8h, t8l, nullptr, nullptr, nullptr, nullptr, nullptr);
  mconv<9, 8, 1, 81, 21, 16, 4, 4, 8, 4><<<dim3(64, 8, 2), blk, 0, stream>>>(
      t8h, t8l, wAm_hi, wAm_lo, P1h, P1l, nullptr, c_sp1, nullptr, 0, 0);
  for (int bc = 0; bc < 2; ++bc) {
    mconv<3, 128, 16, 9, 3, 16, 4, 4, 8, 4><<<dim3(64, 4, 2), blk, 0, stream>>>(
        P1h, P1l, wC2_hi, wC2_lo, P2h, P2l, nullptr, c_sp2, nullptr, bc * 4, 0);
    mconv<3, 128, 16, 9, 3, 16, 4, 4, 8, 2><<<dim3(64, 4, 2), blk, 0, stream>>>(
        P2h, P2l, wC3_hi, wC3_lo, nullptr, nullptr, mask_c, c_sp3, scal, 0, bc * 4);
  }

  // rn slots 7..13, den slots 6 (scratch) + 7..12 — spatial mask -> EPI3
  BtB(xbuf, Bp, denbuf + 6 * 8, nullptr, nullptr, nullptr, nullptr, false);
  k_cg0p<<<cgrid, blk, 0, stream>>>(bimg, Bp, rbuf, pbuf, rnbuf + 7 * 8);
  {
    float* pc = pbuf;
    float* pa = pbuf2;
    for (int it = 0; it < 6; ++it) {
      if (it == 0) {
        BtB(pc, Bp, denbuf + (7 + it) * 8, nullptr, nullptr, nullptr, nullptr, false);
      } else {
        BtB(nullptr, Bp, denbuf + (7 + it) * 8,
            rnbuf + (7 + it - 1) * 8, rnbuf + (7 + it) * 8, pc, pa, false);
        float* t = pc; pc = pa; pa = t;
      }
      float* xout = (it == 5) ? (float*)d_out : nullptr;
      k_cg2a<<<cgrid, blk, 0, stream>>>(xbuf, rbuf, pc, Bp,
          rnbuf + (7 + it) * 8, denbuf + (7 + it) * 8, rnbuf + (8 + it) * 8, xout);
    }
  }
}